// Round 1
// 484.755 us; speedup vs baseline: 1.0378x; 1.0378x over previous
//
#include <hip/hip_runtime.h>
#include <hip/hip_bf16.h>

#define N_NODES   50000
#define N_EDGES   500000
#define NHEAD     8
#define NUM_KEYS  8
#define NUM_ETYPES 4
#define NUM_BLOCKS 2
#define N_TARGETS 128
#define NPAD      51200   // 400 tiles * 128
#define NTILES    400
#define NBLK      196     // ceil(N_NODES/256)
#define LDW       136     // u16 LDS stride (16B-aligned rows)
#define LDWF      132     // f32 LDS stride
#define QKVW      1152    // unified row: [q 128 | k 512 | v 512]
#define SCAP      45      // LDS sort scratch per thread (odd stride -> conflict-light)

typedef unsigned short u16;
typedef unsigned int   u32;
typedef __attribute__((ext_vector_type(8))) short short8;
typedef __attribute__((ext_vector_type(4))) short short4v;
typedef __attribute__((ext_vector_type(4))) float floatx4;
typedef __attribute__((ext_vector_type(2))) float f32x2;

// packed (fragment-major) address within a 128x128 u16 tile:
// elem(row r, col c) -> (c>>3)*1024 + r*8 + (c&7).
__device__ __forceinline__ size_t pkaddr(int tile, int r, int c){
  return (size_t)tile * 16384 + ((c >> 3) << 10) + (r << 3) + (c & 7);
}

// ---------- bf16 helpers ----------
__device__ __forceinline__ float bflo(u32 u)  { return __uint_as_float(u << 16); }
__device__ __forceinline__ float bfhi(u32 u)  { return __uint_as_float(u & 0xffff0000u); }
__device__ __forceinline__ float bf2f(u16 u)  { return __uint_as_float(((u32)u) << 16); }
__device__ __forceinline__ u16   f2bf(float f){
  u32 u = __float_as_uint(f);
  u += 0x7fffu + ((u >> 16) & 1u);
  return (u16)(u >> 16);
}
__device__ __forceinline__ f32x2 up2(u32 u){
  f32x2 r; r.x = bflo(u); r.y = bfhi(u); return r;
}

// ---------- dtype detector ----------
__global__ void detect_dtype(const u16* raw, int* flag){
  __shared__ int cnt;
  if (threadIdx.x == 0) cnt = 0;
  __syncthreads();
  int sane = 0;
  #pragma unroll
  for (int k = 0; k < 4; k++){
    u16 u = raw[threadIdx.x * 4 + k];
    int e = (u >> 7) & 0xff;
    if (e >= 100 && e <= 145) sane++;
  }
  atomicAdd(&cnt, sane);
  __syncthreads();
  if (threadIdx.x == 0) *flag = (cnt >= 870) ? 1 : 0;
}

// ---------- fused weight conversion (was 7 launches -> 1) ----------
// blocks 0..1023: qw -> qwc (packed); 1024..2047: nw -> nwc (packed);
// 2048..3071: kw/vw -> kvw (packed, [blk][k|v]); 3072..3079: tw -> twf (f32);
// 3080: ln_gamma -> gbf[0..255]; 3081: ln_beta -> gbf[256..511].
__global__ void cvt_all(const void* qw, const void* nw, const void* kw, const void* vw,
                        const void* tw, const void* lgp, const void* lbp,
                        u16* __restrict__ qwc, u16* __restrict__ nwc, u16* __restrict__ kvw,
                        float* __restrict__ twf, float* __restrict__ gbf,
                        const int* __restrict__ flag){
  int b = blockIdx.x, t = threadIdx.x;
  int fl = *flag;
  if (b < 2048){
    const void* src = (b < 1024) ? qw : nw;
    u16* dst = (b < 1024) ? qwc : nwc;
    int i = ((b & 1023) << 8) + t;
    u16 v = fl ? ((const u16*)src)[i] : f2bf(((const float*)src)[i]);
    int mat = i >> 14, rem = i & 16383;
    dst[pkaddr(mat, rem >> 7, rem & 127)] = v;
  } else if (b < 3072){
    int r = b - 2048;
    int blk = r >> 9, half = (r >> 8) & 1;
    int i = ((r & 255) << 8) + t;                  // 0..65535 within (blk,half)
    const void* src = half ? vw : kw;
    size_t soff = (size_t)blk * 65536 + i;
    u16 v = fl ? ((const u16*)src)[soff] : f2bf(((const float*)src)[soff]);
    int mat = i >> 14, rem = i & 16383;
    kvw[(size_t)blk * 131072 + (size_t)half * 65536 + pkaddr(mat, rem >> 7, rem & 127)] = v;
  } else if (b < 3080){
    int i = ((b - 3072) << 8) + t;
    twf[i] = fl ? bf2f(((const u16*)tw)[i]) : ((const float*)tw)[i];
  } else if (b == 3080){
    gbf[t] = fl ? bf2f(((const u16*)lgp)[t]) : ((const float*)lgp)[t];
  } else {
    gbf[256 + t] = fl ? bf2f(((const u16*)lbp)[t]) : ((const float*)lbp)[t];
  }
}

// ---------- contention-free, deterministic key-bucket counting sort ----------
__global__ void khist_blk(const int* __restrict__ key_ids, int* __restrict__ blkcnt){
  __shared__ int c[8];
  int t = threadIdx.x, b = blockIdx.x;
  if (t < 8) c[t] = 0;
  __syncthreads();
  int n = b * 256 + t;
  if (n < N_NODES) atomicAdd(&c[key_ids[n]], 1);
  __syncthreads();
  if (t < 8) blkcnt[t * NBLK + b] = c[t];
}
__global__ void kscan2(const int* __restrict__ blkcnt, int* __restrict__ base,
                       int* __restrict__ tile_key){
  __shared__ int po[8];
  __shared__ int tot[8];
  int t = threadIdx.x;  // 64 threads
  if (t < 8){
    int s = 0;
    for (int b = 0; b < NBLK; b++) s += blkcnt[t * NBLK + b];
    tot[t] = s;
  }
  __syncthreads();
  if (t == 0){
    int off = 0;
    for (int k = 0; k < 8; k++){ po[k] = off; off += ((tot[k] + 127) >> 7) << 7; }
  }
  __syncthreads();
  if (t < 8){
    int run = po[t];
    for (int b = 0; b < NBLK; b++){ base[t * NBLK + b] = run; run += blkcnt[t * NBLK + b]; }
  }
  for (int tt = t; tt < NTILES; tt += 64){
    int row = tt << 7, k = 7;
    for (int kk = 1; kk < 8; kk++)
      if (row < po[kk]){ k = kk - 1; break; }
    tile_key[tt] = k;
  }
}
__global__ void scatter_perm2(const int* __restrict__ key_ids, const int* __restrict__ base,
                              int* __restrict__ perm, int* __restrict__ invperm){
  __shared__ unsigned char keyarr[256];
  int t = threadIdx.x, b = blockIdx.x;
  int n = b * 256 + t;
  int key = (n < N_NODES) ? key_ids[n] : 8;
  keyarr[t] = (unsigned char)key;
  __syncthreads();
  if (n >= N_NODES) return;
  int rank = 0;
  for (int j = 0; j < t; j++) rank += (keyarr[j] == (unsigned char)key);
  int pos = base[key * NBLK + b] + rank;
  perm[pos] = n;
  invperm[n] = pos;
}

// ---------- feat gather: f32 linear + hi/lo bf16 packed (also zeroes deg) ----------
__global__ void gather_feat(const void* emb_raw, const int* __restrict__ vid,
                            const int* __restrict__ perm, const int* __restrict__ flag,
                            float* __restrict__ feat, u16* __restrict__ fhi,
                            u16* __restrict__ flo, int* __restrict__ deg){
  int i = blockIdx.x * 256 + threadIdx.x;          // NPAD*128 exact
  int n = i >> 7, d = i & 127;
  if (d == 0) deg[n] = 0;
  int e = (vid[perm[n]] << 7) + d;
  float v = (*flag) ? bf2f(((const u16*)emb_raw)[e]) : ((const float*)emb_raw)[e];
  feat[i] = v;
  u16 h = f2bf(v);
  size_t pa = pkaddr(n >> 7, n & 127, d);
  fhi[pa] = h;
  flo[pa] = f2bf(v - bf2f(h));
}

// ---------- CSR build (perm space) ----------
__global__ void hist_dst(const int* __restrict__ dst, const int* __restrict__ invp,
                         int* __restrict__ deg){
  int e = blockIdx.x * 256 + threadIdx.x;
  if (e < N_EDGES) atomicAdd(&deg[invp[dst[e]]], 1);
}
__global__ __launch_bounds__(1024) void scan_deg(const int* __restrict__ deg,
                                                 int* __restrict__ rs, int* __restrict__ cur){
  __shared__ int s[1024];
  int t = threadIdx.x;
  int lo = t * 50, hi = lo + 50;                    // 1024*50 = NPAD
  int sum = 0;
  for (int i = lo; i < hi; i++) sum += deg[i];
  s[t] = sum;
  __syncthreads();
  for (int off = 1; off < 1024; off <<= 1){
    int v = (t >= off) ? s[t - off] : 0;
    __syncthreads();
    s[t] += v;
    __syncthreads();
  }
  int run = s[t] - sum;
  for (int i = lo; i < hi; i++){
    rs[i] = run; cur[i] = run;
    run += deg[i];
  }
}
__global__ void scatter_edges(const int* __restrict__ src, const int* __restrict__ dst,
                              const int* __restrict__ et, const int* __restrict__ invp,
                              int* __restrict__ cur, u32* __restrict__ epk){
  int e = blockIdx.x * 256 + threadIdx.x;
  if (e >= N_EDGES) return;
  int pos = atomicAdd(&cur[invp[dst[e]]], 1);
  epk[pos] = ((u32)invp[src[e]] << 2) | (u32)et[e];
}
// canonicalize within-node edge order (determinism). LDS-cached insertion sort.
__global__ __launch_bounds__(256) void sort_csr(const int* __restrict__ rs,
                                                const int* __restrict__ deg,
                                                u32* __restrict__ epk){
  __shared__ u32 buf[256 * SCAP];
  int t = threadIdx.x;
  int n = blockIdx.x * 256 + t;
  if (n >= NPAD) return;
  int s = rs[n], c = deg[n];
  if (c <= 1) return;
  if (c <= SCAP){
    u32* b = buf + t * SCAP;
    for (int i = 0; i < c; i++) b[i] = epk[s + i];
    for (int i = 1; i < c; i++){
      u32 v = b[i];
      int j = i - 1;
      while (j >= 0 && b[j] > v){ b[j + 1] = b[j]; j--; }
      b[j + 1] = v;
    }
    for (int i = 0; i < c; i++) epk[s + i] = b[i];
  } else {
    for (int i = 1; i < c; i++){
      u32 v = epk[s + i];
      int j = i - 1;
      while (j >= 0 && epk[s + j] > v){ epk[s + j + 1] = epk[s + j]; j--; }
      epk[s + j + 1] = v;
    }
  }
}

// ---------- unified q+kv MFMA GEMM, packed operands, XCD-affine swizzle ----------
__global__ __launch_bounds__(256) void gemm_qkv(
    const u16* __restrict__ Ahi, const u16* __restrict__ Alo,
    const u16* __restrict__ Qw, const u16* __restrict__ KVw,
    const int* __restrict__ tkey, u16* __restrict__ C)
{
  __shared__ u16 sc[128 * LDW];
  int id = blockIdx.x;
  int xcd = id & 7, wi = id >> 3;        // wi in [0,450)
  int cy = xcd * 50 + wi / 9;            // row tile
  int cx = wi % 9;                       // column tile: 0=q, 1..8=kv
  int m0 = cy * 128;
  const u16* Bte = (cx == 0) ? (Qw + (size_t)tkey[cy] * 16384)
                             : (KVw + (size_t)(cx - 1) * 16384);
  const u16* Ath = Ahi + (size_t)cy * 16384;
  const u16* Atl = Alo + (size_t)cy * 16384;
  int w = threadIdx.x >> 6, l = threadIdx.x & 63;
  int wm = (w & 1) * 64, wn = (w >> 1) * 64;
  int lr = l & 15, lg = l >> 4;
  floatx4 acc[4][4] = {};
  #pragma unroll
  for (int kk = 0; kk < 4; kk++){
    int cc10 = (kk * 4 + lg) << 10;      // chunk base in packed tile
    short8 ah[4], al[4], bfr[4];
    #pragma unroll
    for (int i = 0; i < 4; i++){
      int off = cc10 + ((wm + i * 16 + lr) << 3);
      ah[i] = *(const short8*)(Ath + off);
      al[i] = *(const short8*)(Atl + off);
    }
    #pragma unroll
    for (int j = 0; j < 4; j++)
      bfr[j] = *(const short8*)(Bte + cc10 + ((wn + j * 16 + lr) << 3));
    #pragma unroll
    for (int i = 0; i < 4; i++)
      #pragma unroll
      for (int j = 0; j < 4; j++){
        acc[i][j] = __builtin_amdgcn_mfma_f32_16x16x32_bf16(ah[i], bfr[j], acc[i][j], 0, 0, 0);
        acc[i][j] = __builtin_amdgcn_mfma_f32_16x16x32_bf16(al[i], bfr[j], acc[i][j], 0, 0, 0);
      }
  }
  #pragma unroll
  for (int i = 0; i < 4; i++)
    #pragma unroll
    for (int j = 0; j < 4; j++)
      #pragma unroll
      for (int r = 0; r < 4; r++)
        sc[(wm + i * 16 + lg * 4 + r) * LDW + wn + j * 16 + lr] = f2bf(acc[i][j][r]);
  __syncthreads();
  int tr = threadIdx.x >> 4, tc = (threadIdx.x & 15) * 8;
  int cbase = cx * 128;   // q at cols 0..127, kv at 128..1151
  #pragma unroll
  for (int it = 0; it < 8; it++){
    int row = tr + it * 16;
    short8 vv = *(const short8*)(sc + row * LDW + tc);
    *(short8*)(C + (size_t)(m0 + row) * QKVW + cbase + tc) = vv;
  }
}

// ---------- fused node GEMM (packed hi/lo A) + relu + f32 LN + residual ----------
__global__ __launch_bounds__(256) void gemm_h_ln(
    const u16* __restrict__ Ahi, const u16* __restrict__ Alo,
    const u16* __restrict__ Bt, const int* __restrict__ tkey,
    const float* __restrict__ gbf,
    float* __restrict__ feat, u16* __restrict__ fhi, u16* __restrict__ flo, int blk)
{
  __shared__ float scf[64 * LDWF];
  int m0 = blockIdx.x * 64;
  int tile = blockIdx.x >> 1, rbase = (blockIdx.x & 1) * 64;
  const u16* Bte = Bt + (size_t)tkey[tile] * 16384;
  const u16* Ath = Ahi + (size_t)tile * 16384;
  const u16* Atl = Alo + (size_t)tile * 16384;
  int w = threadIdx.x >> 6, l = threadIdx.x & 63;
  int wn = w * 32;
  int lr = l & 15, lg = l >> 4;
  floatx4 acc[4][2] = {};
  #pragma unroll
  for (int kk = 0; kk < 4; kk++){
    int cc10 = (kk * 4 + lg) << 10;
    short8 ah[4], al[4], bfr[2];
    #pragma unroll
    for (int i = 0; i < 4; i++){
      int off = cc10 + ((rbase + i * 16 + lr) << 3);
      ah[i] = *(const short8*)(Ath + off);
      al[i] = *(const short8*)(Atl + off);
    }
    #pragma unroll
    for (int j = 0; j < 2; j++)
      bfr[j] = *(const short8*)(Bte + cc10 + ((wn + j * 16 + lr) << 3));
    #pragma unroll
    for (int i = 0; i < 4; i++)
      #pragma unroll
      for (int j = 0; j < 2; j++){
        acc[i][j] = __builtin_amdgcn_mfma_f32_16x16x32_bf16(ah[i], bfr[j], acc[i][j], 0, 0, 0);
        acc[i][j] = __builtin_amdgcn_mfma_f32_16x16x32_bf16(al[i], bfr[j], acc[i][j], 0, 0, 0);
      }
  }
  #pragma unroll
  for (int i = 0; i < 4; i++)
    #pragma unroll
    for (int j = 0; j < 2; j++)
      #pragma unroll
      for (int r = 0; r < 4; r++)
        scf[(i * 16 + lg * 4 + r) * LDWF + wn + j * 16 + lr] = acc[i][j][r];
  __syncthreads();
  int r = threadIdx.x >> 2, q4 = (threadIdx.x & 3) * 32;
  const float* srow = scf + r * LDWF + q4;
  float s1 = 0.f, s2 = 0.f;
  #pragma unroll
  for (int c = 0; c < 32; c++){
    float v = fmaxf(srow[c], 0.f);
    s1 += v; s2 += v * v;
  }
  s1 += __shfl_xor(s1, 1, 64); s1 += __shfl_xor(s1, 2, 64);
  s2 += __shfl_xor(s2, 1, 64); s2 += __shfl_xor(s2, 2, 64);
  float mu = s1 * (1.f / 128.f);
  float var = s2 * (1.f / 128.f) - mu * mu;
  float rstd = rsqrtf(var + 1e-5f);
  int n = m0 + r;
  int ntile = n >> 7, nr = n & 127;
  float* fr = feat + (size_t)n * 128 + q4;
  const float* gp = gbf + (blk << 7) + q4;
  #pragma unroll
  for (int c = 0; c < 32; c += 4){
    float4 fo = *(float4*)(fr + c);
    float y0 = (fmaxf(srow[c+0], 0.f) - mu) * rstd * gp[c+0] + gp[256 + c + 0] + fo.x;
    float y1 = (fmaxf(srow[c+1], 0.f) - mu) * rstd * gp[c+1] + gp[256 + c + 1] + fo.y;
    float y2 = (fmaxf(srow[c+2], 0.f) - mu) * rstd * gp[c+2] + gp[256 + c + 2] + fo.z;
    float y3 = (fmaxf(srow[c+3], 0.f) - mu) * rstd * gp[c+3] + gp[256 + c + 3] + fo.w;
    *(float4*)(fr + c) = make_float4(y0, y1, y2, y3);
    u16 h0 = f2bf(y0), h1 = f2bf(y1), h2 = f2bf(y2), h3 = f2bf(y3);
    size_t pa = pkaddr(ntile, nr, q4 + c);   // q4+c mult of 4 -> within one 8-chunk
    short4v ph; ph.x = (short)h0; ph.y = (short)h1; ph.z = (short)h2; ph.w = (short)h3;
    *(short4v*)(fhi + pa) = ph;
    short4v pl;
    pl.x = (short)f2bf(y0 - bf2f(h0)); pl.y = (short)f2bf(y1 - bf2f(h1));
    pl.z = (short)f2bf(y2 - bf2f(h2)); pl.w = (short)f2bf(y3 - bf2f(h3));
    *(short4v*)(flo + pa) = pl;
  }
}

// ---------- single-pass edge attention (16 lanes/node: 8 heads x 2 slots) ----------
// vs previous 64-lane/node version: reduction 51 -> 17 DS ops per node, q-load
// redundancy 8x -> 2x, branch-free clamped loads (both slots' K/V in flight before
// compute), hoisted q unpack, float2 math for v_pk_fma_f32, 16B contiguous writes.
__global__ __launch_bounds__(256) void edge_attn(
    const u16* __restrict__ qkv,
    const int* __restrict__ rs, const int* __restrict__ deg,
    const u32* __restrict__ epk, u16* __restrict__ agghi, u16* __restrict__ agglo)
{
  int n = blockIdx.x * 16 + (threadIdx.x >> 4);
  int l = threadIdx.x & 15;
  int h = l & 7, s = l >> 3;               // s in {0,1}
  const u16* qp = qkv + (size_t)n * QKVW + (h << 4);
  uint4 q0 = *(const uint4*)qp, q1 = *(const uint4*)(qp + 8);
  f32x2 qv[8];
  qv[0] = up2(q0.x); qv[1] = up2(q0.y); qv[2] = up2(q0.z); qv[3] = up2(q0.w);
  qv[4] = up2(q1.x); qv[5] = up2(q1.y); qv[6] = up2(q1.z); qv[7] = up2(q1.w);
  int e0 = rs[n], cnt = deg[n];
  float z = 0.f;
  f32x2 acc[8];
  #pragma unroll
  for (int j = 0; j < 8; j++){ acc[j].x = 0.f; acc[j].y = 0.f; }
  for (int base = 0; base < cnt; base += 4){
    int i0 = base + s, i1 = base + s + 2;
    bool p0 = i0 < cnt, p1 = i1 < cnt;
    // clamped, unconditional loads: inactive lanes re-read the last edge (L1 hit),
    // contribution zeroed via ew select. Keeps all 8 K/V loads in flight.
    u32 pk0 = epk[e0 + min(i0, cnt - 1)];
    u32 pk1 = epk[e0 + min(i1, cnt - 1)];
    const u16* kp0 = qkv + (size_t)(pk0 >> 2) * QKVW + 128 + ((pk0 & 3) << 7) + (h << 4);
    const u16* kp1 = qkv + (size_t)(pk1 >> 2) * QKVW + 128 + ((pk1 & 3) << 7) + (h << 4);
    uint4 ka0 = *(const uint4*)kp0, kb0 = *(const uint4*)(kp0 + 8);
    uint4 va0 = *(const uint4*)(kp0 + 512), vb0 = *(const uint4*)(kp0 + 520);
    uint4 ka1 = *(const uint4*)kp1, kb1 = *(const uint4*)(kp1 + 8);
    uint4 va1 = *(const uint4*)(kp1 + 512), vb1 = *(const uint4*)(kp1 + 520);
    f32x2 d0 = up2(ka0.x) * qv[0] + up2(ka0.y) * qv[1] + up2(ka0.z) * qv[2] + up2(ka0.w) * qv[3]
             + up2(kb0.x) * qv[4] + up2(kb0.y) * qv[5] + up2(kb0.z) * qv[6] + up2(kb0.w) * qv[7];
    f32x2 d1 = up2(ka1.x) * qv[0] + up2(ka1.y) * qv[1] + up2(ka1.z) * qv[2] + up2(ka1.w) * qv[3]
             + up2(kb1.x) * qv[4] + up2(kb1.y) * qv[5] + up2(kb1.z) * qv[6] + up2(kb1.w) * qv[7];
    float ew0 = p0 ? __expf(fminf((d0.x + d0.y) * 0.25f, 80.f)) : 0.f;
    float ew1 = p1 ? __expf(fminf((d1.x + d1.y) * 0.25f, 80.f)) : 0.f;
    z += ew0 + ew1;
    f32x2 w0v; w0v.x = ew0; w0v.y = ew0;
    f32x2 w1v; w1v.x = ew1; w1v.y = ew1;
    acc[0] += w0v * up2(va0.x); acc[1] += w0v * up2(va0.y);
    acc[2] += w0v * up2(va0.z); acc[3] += w0v * up2(va0.w);
    acc[4] += w0v * up2(vb0.x); acc[5] += w0v * up2(vb0.y);
    acc[6] += w0v * up2(vb0.z); acc[7] += w0v * up2(vb0.w);
    acc[0] += w1v * up2(va1.x); acc[1] += w1v * up2(va1.y);
    acc[2] += w1v * up2(va1.z); acc[3] += w1v * up2(va1.w);
    acc[4] += w1v * up2(vb1.x); acc[5] += w1v * up2(vb1.y);
    acc[6] += w1v * up2(vb1.z); acc[7] += w1v * up2(vb1.w);
  }
  // single butterfly round across the 2 slots (lane l <-> l^8)
  z += __shfl_xor(z, 8, 64);
  #pragma unroll
  for (int j = 0; j < 8; j++){
    acc[j].x += __shfl_xor(acc[j].x, 8, 64);
    acc[j].y += __shfl_xor(acc[j].y, 8, 64);
  }
  float inv = 1.f / (z + 1e-9f);
  float xv[8];
  if (s == 0){
    xv[0] = acc[0].x; xv[1] = acc[0].y; xv[2] = acc[1].x; xv[3] = acc[1].y;
    xv[4] = acc[2].x; xv[5] = acc[2].y; xv[6] = acc[3].x; xv[7] = acc[3].y;
  } else {
    xv[0] = acc[4].x; xv[1] = acc[4].y; xv[2] = acc[5].x; xv[3] = acc[5].y;
    xv[4] = acc[6].x; xv[5] = acc[6].y; xv[6] = acc[7].x; xv[7] = acc[7].y;
  }
  short8 ph, pl;
  #pragma unroll
  for (int k = 0; k < 8; k++){
    float y = xv[k] * inv;
    u16 hk = f2bf(y);
    ph[k] = (short)hk;
    pl[k] = (short)f2bf(y - bf2f(hk));
  }
  size_t pa = pkaddr(n >> 7, n & 127, (h << 4) + (s << 3));  // one aligned 8-chunk
  *(short8*)(agghi + pa) = ph;
  *(short8*)(agglo + pa) = pl;
}

// ---------- target readout ----------
__global__ __launch_bounds__(128) void readout(
    const float* __restrict__ feat, const float* __restrict__ twf,
    const int* __restrict__ key_ids, const int* __restrict__ invp,
    const int* __restrict__ tgt,
    float* __restrict__ outacc, void* dout, const int* __restrict__ flag, int blk)
{
  int t = threadIdx.x;
  int n = tgt[t];
  int key = key_ids[n];
  const float4* fr = (const float4*)(feat + (size_t)invp[n] * 128);
  const float4* wr = (const float4*)(twf + (size_t)((blk * 8 + key) << 7));
  float acc = 0.f;
  #pragma unroll
  for (int d = 0; d < 32; d++){
    float4 a = fr[d], b = wr[d];
    acc += a.x * b.x + a.y * b.y + a.z * b.z + a.w * b.w;
  }
  if (blk == 0){
    outacc[t] = 0.5f * acc;
  } else {
    float r = outacc[t] + 0.5f * acc;
    if (*flag) ((u16*)dout)[t] = f2bf(r);
    else       ((float*)dout)[t] = r;
  }
}

extern "C" void kernel_launch(void* const* d_in, const int* in_sizes, int n_in,
                              void* d_out, int out_size, void* d_ws, size_t ws_size,
                              hipStream_t stream)
{
  const void* emb = d_in[0];
  const void* qw  = d_in[1];
  const void* kw  = d_in[2];
  const void* vw  = d_in[3];
  const void* nw  = d_in[4];
  const void* tw  = d_in[5];
  const void* lg  = d_in[6];
  const void* lb  = d_in[7];
  const int* value_ids = (const int*)d_in[8];
  const int* key_ids   = (const int*)d_in[9];
  const int* srcp  = (const int*)d_in[10];
  const int* dstp  = (const int*)d_in[11];
  const int* etp   = (const int*)d_in[12];
  const int* tgt   = (const int*)d_in[13];

  char* p = (char*)d_ws;
  auto carve = [&](size_t bytes)->char*{
    char* r = p; p += (bytes + 255) & ~(size_t)255; return r;
  };
  int*   flag    = (int*)  carve(4);
  float* featp   = (float*)carve((size_t)NPAD * 128 * 4);
  u16*   feathi  = (u16*)  carve((size_t)NPAD * 128 * 2);
  u16*   featlo  = (u16*)  carve((size_t)NPAD * 128 * 2);
  u16*   qwc     = (u16*)  carve((size_t)2 * 1024 * 128 * 2);
  u16*   kvw     = (u16*)  carve((size_t)2 * 1024 * 128 * 2);
  u16*   nwc     = (u16*)  carve((size_t)2 * 1024 * 128 * 2);
  float* twf     = (float*)carve((size_t)2048 * 4);
  float* gbf     = (float*)carve((size_t)512 * 4);
  int*   blkcnt  = (int*)  carve((size_t)8 * NBLK * 4);
  int*   kbase   = (int*)  carve((size_t)8 * NBLK * 4);
  int*   tile_key= (int*)  carve(NTILES * 4);
  int*   perm    = (int*)  carve((size_t)NPAD * 4);
  int*   invperm = (int*)  carve((size_t)N_NODES * 4);
  int*   deg     = (int*)  carve((size_t)NPAD * 4);
  int*   rsx     = (int*)  carve((size_t)NPAD * 4);
  int*   cur     = (int*)  carve((size_t)NPAD * 4);
  u32*   epk     = (u32*)  carve((size_t)N_EDGES * 4);
  u16*   qkvbuf  = (u16*)  carve((size_t)NPAD * QKVW * 2);
  u16*   agghi   = (u16*)  carve((size_t)NPAD * 128 * 2);
  u16*   agglo   = (u16*)  carve((size_t)NPAD * 128 * 2);
  float* outacc  = (float*)carve((size_t)N_TARGETS * 4);
  (void)ws_size; (void)n_in; (void)in_sizes; (void)out_size;

  detect_dtype<<<1, 256, 0, stream>>>((const u16*)emb, flag);

  // fused weight/param conversion: 1 launch replaces 7
  cvt_all<<<3082, 256, 0, stream>>>(qw, nw, kw, vw, tw, lg, lb,
                                    qwc, nwc, kvw, twf, gbf, flag);

  // deterministic key-bucket counting sort
  hipMemsetAsync(perm, 0, (size_t)NPAD * 4, stream);
  khist_blk<<<NBLK, 256, 0, stream>>>(key_ids, blkcnt);
  kscan2<<<1, 64, 0, stream>>>(blkcnt, kbase, tile_key);
  scatter_perm2<<<NBLK, 256, 0, stream>>>(key_ids, kbase, perm, invperm);

  gather_feat<<<(NPAD * 128) / 256, 256, 0, stream>>>(emb, value_ids, perm, flag,
                                                      featp, feathi, featlo, deg);

  // CSR in perm space; canonicalize per-node edge order for determinism
  const int eg = (N_EDGES + 255) / 256;
  hist_dst<<<eg, 256, 0, stream>>>(dstp, invperm, deg);
  scan_deg<<<1, 1024, 0, stream>>>(deg, rsx, cur);
  scatter_edges<<<eg, 256, 0, stream>>>(srcp, dstp, etp, invperm, cur, epk);
  sort_csr<<<(NPAD + 255) / 256, 256, 0, stream>>>(rsx, deg, epk);

  for (int b = 0; b < NUM_BLOCKS; b++){
    gemm_qkv<<<3600, 256, 0, stream>>>(feathi, featlo,
                                       qwc + (size_t)b * 1024 * 128,
                                       kvw + (size_t)b * 1024 * 128,
                                       tile_key, qkvbuf);
    edge_attn<<<NPAD / 16, 256, 0, stream>>>(qkvbuf, rsx, deg, epk, agghi, agglo);
    gemm_h_ln<<<NPAD / 64, 256, 0, stream>>>(agghi, agglo,
                                             nwc + (size_t)b * 1024 * 128,
                                             tile_key, gbf, featp, feathi, featlo, b);
    readout<<<1, 128, 0, stream>>>(featp, twf, key_ids, invperm, tgt, outacc, d_out, flag, b);
  }
}

// Round 5
// 483.982 us; speedup vs baseline: 1.0394x; 1.0016x over previous
//
#include <hip/hip_runtime.h>
#include <hip/hip_bf16.h>

#define N_NODES   50000
#define N_EDGES   500000
#define NHEAD     8
#define NUM_KEYS  8
#define NUM_ETYPES 4
#define NUM_BLOCKS 2
#define N_TARGETS 128
#define NPAD      51200   // 400 tiles * 128
#define NTILES    400
#define NBLK      196     // ceil(N_NODES/256)
#define LDW       136     // u16 LDS stride (16B-aligned rows)
#define LDWF      132     // f32 LDS stride
#define QKVW      1152    // unified row: [q 128 | k 512 | v 512]
#define SCAP      45      // LDS sort scratch per thread (odd stride -> conflict-light)

typedef unsigned short u16;
typedef unsigned int   u32;
typedef __attribute__((ext_vector_type(8))) short short8;
typedef __attribute__((ext_vector_type(4))) short short4v;
typedef __attribute__((ext_vector_type(4))) float floatx4;
typedef __attribute__((ext_vector_type(2))) float f32x2;

// packed (fragment-major) address within a 128x128 u16 tile:
// elem(row r, col c) -> (c>>3)*1024 + r*8 + (c&7).
__device__ __forceinline__ size_t pkaddr(int tile, int r, int c){
  return (size_t)tile * 16384 + ((c >> 3) << 10) + (r << 3) + (c & 7);
}

// ---------- bf16 helpers ----------
__device__ __forceinline__ float bflo(u32 u)  { return __uint_as_float(u << 16); }
__device__ __forceinline__ float bfhi(u32 u)  { return __uint_as_float(u & 0xffff0000u); }
__device__ __forceinline__ float bf2f(u16 u)  { return __uint_as_float(((u32)u) << 16); }
__device__ __forceinline__ u16   f2bf(float f){
  u32 u = __float_as_uint(f);
  u += 0x7fffu + ((u >> 16) & 1u);
  return (u16)(u >> 16);
}
__device__ __forceinline__ f32x2 up2(u32 u){
  f32x2 r; r.x = bflo(u); r.y = bfhi(u); return r;
}

// ---------- dtype detector ----------
__global__ void detect_dtype(const u16* raw, int* flag){
  __shared__ int cnt;
  if (threadIdx.x == 0) cnt = 0;
  __syncthreads();
  int sane = 0;
  #pragma unroll
  for (int k = 0; k < 4; k++){
    u16 u = raw[threadIdx.x * 4 + k];
    int e = (u >> 7) & 0xff;
    if (e >= 100 && e <= 145) sane++;
  }
  atomicAdd(&cnt, sane);
  __syncthreads();
  if (threadIdx.x == 0) *flag = (cnt >= 870) ? 1 : 0;
}

// ---------- fused weight conversion (+ perm zeroing folded in) ----------
// blocks 0..1023: qw -> qwc (packed); 1024..2047: nw -> nwc (packed);
// 2048..3071: kw/vw -> kvw (packed, [blk][k|v]); 3072..3079: tw -> twf (f32);
// 3080: ln_gamma; 3081: ln_beta; 3082..3281: zero perm (integer-only, replaces
// the standalone hipMemsetAsync dispatch).
__global__ void cvt_all(const void* qw, const void* nw, const void* kw, const void* vw,
                        const void* tw, const void* lgp, const void* lbp,
                        u16* __restrict__ qwc, u16* __restrict__ nwc, u16* __restrict__ kvw,
                        float* __restrict__ twf, float* __restrict__ gbf,
                        int* __restrict__ perm,
                        const int* __restrict__ flag){
  int b = blockIdx.x, t = threadIdx.x;
  if (b >= 3082){
    perm[((b - 3082) << 8) + t] = 0;
    return;
  }
  int fl = *flag;
  if (b < 2048){
    const void* src = (b < 1024) ? qw : nw;
    u16* dst = (b < 1024) ? qwc : nwc;
    int i = ((b & 1023) << 8) + t;
    u16 v = fl ? ((const u16*)src)[i] : f2bf(((const float*)src)[i]);
    int mat = i >> 14, rem = i & 16383;
    dst[pkaddr(mat, rem >> 7, rem & 127)] = v;
  } else if (b < 3072){
    int r = b - 2048;
    int blk = r >> 9, half = (r >> 8) & 1;
    int i = ((r & 255) << 8) + t;                  // 0..65535 within (blk,half)
    const void* src = half ? vw : kw;
    size_t soff = (size_t)blk * 65536 + i;
    u16 v = fl ? ((const u16*)src)[soff] : f2bf(((const float*)src)[soff]);
    int mat = i >> 14, rem = i & 16383;
    kvw[(size_t)blk * 131072 + (size_t)half * 65536 + pkaddr(mat, rem >> 7, rem & 127)] = v;
  } else if (b < 3080){
    int i = ((b - 3072) << 8) + t;
    twf[i] = fl ? bf2f(((const u16*)tw)[i]) : ((const float*)tw)[i];
  } else if (b == 3080){
    gbf[t] = fl ? bf2f(((const u16*)lgp)[t]) : ((const float*)lgp)[t];
  } else {
    gbf[256 + t] = fl ? bf2f(((const u16*)lbp)[t]) : ((const float*)lbp)[t];
  }
}

// ---------- contention-free, deterministic key-bucket counting sort ----------
__global__ void khist_blk(const int* __restrict__ key_ids, int* __restrict__ blkcnt){
  __shared__ int c[8];
  int t = threadIdx.x, b = blockIdx.x;
  if (t < 8) c[t] = 0;
  __syncthreads();
  int n = b * 256 + t;
  if (n < N_NODES) atomicAdd(&c[key_ids[n]], 1);
  __syncthreads();
  if (t < 8) blkcnt[t * NBLK + b] = c[t];
}
__global__ void kscan2(const int* __restrict__ blkcnt, int* __restrict__ base,
                       int* __restrict__ tile_key){
  __shared__ int po[8];
  __shared__ int tot[8];
  int t = threadIdx.x;  // 64 threads
  if (t < 8){
    int s = 0;
    for (int b = 0; b < NBLK; b++) s += blkcnt[t * NBLK + b];
    tot[t] = s;
  }
  __syncthreads();
  if (t == 0){
    int off = 0;
    for (int k = 0; k < 8; k++){ po[k] = off; off += ((tot[k] + 127) >> 7) << 7; }
  }
  __syncthreads();
  if (t < 8){
    int run = po[t];
    for (int b = 0; b < NBLK; b++){ base[t * NBLK + b] = run; run += blkcnt[t * NBLK + b]; }
  }
  for (int tt = t; tt < NTILES; tt += 64){
    int row = tt << 7, k = 7;
    for (int kk = 1; kk < 8; kk++)
      if (row < po[kk]){ k = kk - 1; break; }
    tile_key[tt] = k;
  }
}
__global__ void scatter_perm2(const int* __restrict__ key_ids, const int* __restrict__ base,
                              int* __restrict__ perm, int* __restrict__ invperm){
  __shared__ unsigned char keyarr[256];
  int t = threadIdx.x, b = blockIdx.x;
  int n = b * 256 + t;
  int key = (n < N_NODES) ? key_ids[n] : 8;
  keyarr[t] = (unsigned char)key;
  __syncthreads();
  if (n >= N_NODES) return;
  int rank = 0;
  for (int j = 0; j < t; j++) rank += (keyarr[j] == (unsigned char)key);
  int pos = base[key * NBLK + b] + rank;
  perm[pos] = n;
  invperm[n] = pos;
}

// ---------- feat gather: f32 linear + hi/lo bf16 packed (also zeroes deg) ----------
__global__ void gather_feat(const void* emb_raw, const int* __restrict__ vid,
                            const int* __restrict__ perm, const int* __restrict__ flag,
                            float* __restrict__ feat, u16* __restrict__ fhi,
                            u16* __restrict__ flo, int* __restrict__ deg){
  int i = blockIdx.x * 256 + threadIdx.x;          // NPAD*128 exact
  int n = i >> 7, d = i & 127;
  if (d == 0) deg[n] = 0;
  int e = (vid[perm[n]] << 7) + d;
  float v = (*flag) ? bf2f(((const u16*)emb_raw)[e]) : ((const float*)emb_raw)[e];
  feat[i] = v;
  u16 h = f2bf(v);
  size_t pa = pkaddr(n >> 7, n & 127, d);
  fhi[pa] = h;
  flo[pa] = f2bf(v - bf2f(h));
}

// ---------- CSR build (perm space) ----------
__global__ void hist_dst(const int* __restrict__ dst, const int* __restrict__ invp,
                         int* __restrict__ deg){
  int e = blockIdx.x * 256 + threadIdx.x;
  if (e < N_EDGES) atomicAdd(&deg[invp[dst[e]]], 1);
}
__global__ __launch_bounds__(1024) void scan_deg(const int* __restrict__ deg,
                                                 int* __restrict__ rs, int* __restrict__ cur){
  __shared__ int s[1024];
  int t = threadIdx.x;
  int lo = t * 50, hi = lo + 50;                    // 1024*50 = NPAD
  int sum = 0;
  for (int i = lo; i < hi; i++) sum += deg[i];
  s[t] = sum;
  __syncthreads();
  for (int off = 1; off < 1024; off <<= 1){
    int v = (t >= off) ? s[t - off] : 0;
    __syncthreads();
    s[t] += v;
    __syncthreads();
  }
  int run = s[t] - sum;
  for (int i = lo; i < hi; i++){
    rs[i] = run; cur[i] = run;
    run += deg[i];
  }
}
__global__ void scatter_edges(const int* __restrict__ src, const int* __restrict__ dst,
                              const int* __restrict__ et, const int* __restrict__ invp,
                              int* __restrict__ cur, u32* __restrict__ epk){
  int e = blockIdx.x * 256 + threadIdx.x;
  if (e >= N_EDGES) return;
  int pos = atomicAdd(&cur[invp[dst[e]]], 1);
  epk[pos] = ((u32)invp[src[e]] << 2) | (u32)et[e];
}
// canonicalize within-node edge order (determinism). LDS-cached insertion sort.
__global__ __launch_bounds__(256) void sort_csr(const int* __restrict__ rs,
                                                const int* __restrict__ deg,
                                                u32* __restrict__ epk){
  __shared__ u32 buf[256 * SCAP];
  int t = threadIdx.x;
  int n = blockIdx.x * 256 + t;
  if (n >= NPAD) return;
  int s = rs[n], c = deg[n];
  if (c <= 1) return;
  if (c <= SCAP){
    u32* b = buf + t * SCAP;
    for (int i = 0; i < c; i++) b[i] = epk[s + i];
    for (int i = 1; i < c; i++){
      u32 v = b[i];
      int j = i - 1;
      while (j >= 0 && b[j] > v){ b[j + 1] = b[j]; j--; }
      b[j + 1] = v;
    }
    for (int i = 0; i < c; i++) epk[s + i] = b[i];
  } else {
    for (int i = 1; i < c; i++){
      u32 v = epk[s + i];
      int j = i - 1;
      while (j >= 0 && epk[s + j] > v){ epk[s + j + 1] = epk[s + j]; j--; }
      epk[s + j + 1] = v;
    }
  }
}

// ---------- unified q+kv MFMA GEMM, packed operands, XCD-affine swizzle ----------
__global__ __launch_bounds__(256) void gemm_qkv(
    const u16* __restrict__ Ahi, const u16* __restrict__ Alo,
    const u16* __restrict__ Qw, const u16* __restrict__ KVw,
    const int* __restrict__ tkey, u16* __restrict__ C)
{
  __shared__ u16 sc[128 * LDW];
  int id = blockIdx.x;
  int xcd = id & 7, wi = id >> 3;        // wi in [0,450)
  int cy = xcd * 50 + wi / 9;            // row tile
  int cx = wi % 9;                       // column tile: 0=q, 1..8=kv
  int m0 = cy * 128;
  const u16* Bte = (cx == 0) ? (Qw + (size_t)tkey[cy] * 16384)
                             : (KVw + (size_t)(cx - 1) * 16384);
  const u16* Ath = Ahi + (size_t)cy * 16384;
  const u16* Atl = Alo + (size_t)cy * 16384;
  int w = threadIdx.x >> 6, l = threadIdx.x & 63;
  int wm = (w & 1) * 64, wn = (w >> 1) * 64;
  int lr = l & 15, lg = l >> 4;
  floatx4 acc[4][4] = {};
  #pragma unroll
  for (int kk = 0; kk < 4; kk++){
    int cc10 = (kk * 4 + lg) << 10;      // chunk base in packed tile
    short8 ah[4], al[4], bfr[4];
    #pragma unroll
    for (int i = 0; i < 4; i++){
      int off = cc10 + ((wm + i * 16 + lr) << 3);
      ah[i] = *(const short8*)(Ath + off);
      al[i] = *(const short8*)(Atl + off);
    }
    #pragma unroll
    for (int j = 0; j < 4; j++)
      bfr[j] = *(const short8*)(Bte + cc10 + ((wn + j * 16 + lr) << 3));
    #pragma unroll
    for (int i = 0; i < 4; i++)
      #pragma unroll
      for (int j = 0; j < 4; j++){
        acc[i][j] = __builtin_amdgcn_mfma_f32_16x16x32_bf16(ah[i], bfr[j], acc[i][j], 0, 0, 0);
        acc[i][j] = __builtin_amdgcn_mfma_f32_16x16x32_bf16(al[i], bfr[j], acc[i][j], 0, 0, 0);
      }
  }
  #pragma unroll
  for (int i = 0; i < 4; i++)
    #pragma unroll
    for (int j = 0; j < 4; j++)
      #pragma unroll
      for (int r = 0; r < 4; r++)
        sc[(wm + i * 16 + lg * 4 + r) * LDW + wn + j * 16 + lr] = f2bf(acc[i][j][r]);
  __syncthreads();
  int tr = threadIdx.x >> 4, tc = (threadIdx.x & 15) * 8;
  int cbase = cx * 128;   // q at cols 0..127, kv at 128..1151
  #pragma unroll
  for (int it = 0; it < 8; it++){
    int row = tr + it * 16;
    short8 vv = *(const short8*)(sc + row * LDW + tc);
    *(short8*)(C + (size_t)(m0 + row) * QKVW + cbase + tc) = vv;
  }
}

// ---------- fused node GEMM (packed hi/lo A) + relu + f32 LN + residual ----------
__global__ __launch_bounds__(256) void gemm_h_ln(
    const u16* __restrict__ Ahi, const u16* __restrict__ Alo,
    const u16* __restrict__ Bt, const int* __restrict__ tkey,
    const float* __restrict__ gbf,
    float* __restrict__ feat, u16* __restrict__ fhi, u16* __restrict__ flo, int blk)
{
  __shared__ float scf[64 * LDWF];
  int m0 = blockIdx.x * 64;
  int tile = blockIdx.x >> 1, rbase = (blockIdx.x & 1) * 64;
  const u16* Bte = Bt + (size_t)tkey[tile] * 16384;
  const u16* Ath = Ahi + (size_t)tile * 16384;
  const u16* Atl = Alo + (size_t)tile * 16384;
  int w = threadIdx.x >> 6, l = threadIdx.x & 63;
  int wn = w * 32;
  int lr = l & 15, lg = l >> 4;
  floatx4 acc[4][2] = {};
  #pragma unroll
  for (int kk = 0; kk < 4; kk++){
    int cc10 = (kk * 4 + lg) << 10;
    short8 ah[4], al[4], bfr[2];
    #pragma unroll
    for (int i = 0; i < 4; i++){
      int off = cc10 + ((rbase + i * 16 + lr) << 3);
      ah[i] = *(const short8*)(Ath + off);
      al[i] = *(const short8*)(Atl + off);
    }
    #pragma unroll
    for (int j = 0; j < 2; j++)
      bfr[j] = *(const short8*)(Bte + cc10 + ((wn + j * 16 + lr) << 3));
    #pragma unroll
    for (int i = 0; i < 4; i++)
      #pragma unroll
      for (int j = 0; j < 2; j++){
        acc[i][j] = __builtin_amdgcn_mfma_f32_16x16x32_bf16(ah[i], bfr[j], acc[i][j], 0, 0, 0);
        acc[i][j] = __builtin_amdgcn_mfma_f32_16x16x32_bf16(al[i], bfr[j], acc[i][j], 0, 0, 0);
      }
  }
  #pragma unroll
  for (int i = 0; i < 4; i++)
    #pragma unroll
    for (int j = 0; j < 2; j++)
      #pragma unroll
      for (int r = 0; r < 4; r++)
        scf[(i * 16 + lg * 4 + r) * LDWF + wn + j * 16 + lr] = acc[i][j][r];
  __syncthreads();
  int r = threadIdx.x >> 2, q4 = (threadIdx.x & 3) * 32;
  const float* srow = scf + r * LDWF + q4;
  float s1 = 0.f, s2 = 0.f;
  #pragma unroll
  for (int c = 0; c < 32; c++){
    float v = fmaxf(srow[c], 0.f);
    s1 += v; s2 += v * v;
  }
  s1 += __shfl_xor(s1, 1, 64); s1 += __shfl_xor(s1, 2, 64);
  s2 += __shfl_xor(s2, 1, 64); s2 += __shfl_xor(s2, 2, 64);
  float mu = s1 * (1.f / 128.f);
  float var = s2 * (1.f / 128.f) - mu * mu;
  float rstd = rsqrtf(var + 1e-5f);
  int n = m0 + r;
  int ntile = n >> 7, nr = n & 127;
  float* fr = feat + (size_t)n * 128 + q4;
  const float* gp = gbf + (blk << 7) + q4;
  #pragma unroll
  for (int c = 0; c < 32; c += 4){
    float4 fo = *(float4*)(fr + c);
    float y0 = (fmaxf(srow[c+0], 0.f) - mu) * rstd * gp[c+0] + gp[256 + c + 0] + fo.x;
    float y1 = (fmaxf(srow[c+1], 0.f) - mu) * rstd * gp[c+1] + gp[256 + c + 1] + fo.y;
    float y2 = (fmaxf(srow[c+2], 0.f) - mu) * rstd * gp[c+2] + gp[256 + c + 2] + fo.z;
    float y3 = (fmaxf(srow[c+3], 0.f) - mu) * rstd * gp[c+3] + gp[256 + c + 3] + fo.w;
    *(float4*)(fr + c) = make_float4(y0, y1, y2, y3);
    u16 h0 = f2bf(y0), h1 = f2bf(y1), h2 = f2bf(y2), h3 = f2bf(y3);
    size_t pa = pkaddr(ntile, nr, q4 + c);   // q4+c mult of 4 -> within one 8-chunk
    short4v ph; ph.x = (short)h0; ph.y = (short)h1; ph.z = (short)h2; ph.w = (short)h3;
    *(short4v*)(fhi + pa) = ph;
    short4v pl;
    pl.x = (short)f2bf(y0 - bf2f(h0)); pl.y = (short)f2bf(y1 - bf2f(h1));
    pl.z = (short)f2bf(y2 - bf2f(h2)); pl.w = (short)f2bf(y3 - bf2f(h3));
    *(short4v*)(flo + pa) = pl;
  }
}

// ---------- single-pass edge attention (16 lanes/node: 8 heads x 2 slots) ----------
// vs previous 64-lane/node version: reduction 51 -> 17 DS ops per node, q-load
// redundancy 8x -> 2x, branch-free clamped loads (both slots' K/V in flight before
// compute), hoisted q unpack, float2 math for v_pk_fma_f32, 16B contiguous writes.
__global__ __launch_bounds__(256) void edge_attn(
    const u16* __restrict__ qkv,
    const int* __restrict__ rs, const int* __restrict__ deg,
    const u32* __restrict__ epk, u16* __restrict__ agghi, u16* __restrict__ agglo)
{
  int n = blockIdx.x * 16 + (threadIdx.x >> 4);
  int l = threadIdx.x & 15;
  int h = l & 7, s = l >> 3;               // s in {0,1}
  const u16* qp = qkv + (size_t)n * QKVW + (h << 4);
  uint4 q0 = *(const uint4*)qp, q1 = *(const uint4*)(qp + 8);
  f32x2 qv[8];
  qv[0] = up2(q0.x); qv[1] = up2(q0.y); qv[2] = up2(q0.z); qv[3] = up2(q0.w);
  qv[4] = up2(q1.x); qv[5] = up2(q1.y); qv[6] = up2(q1.z); qv[7] = up2(q1.w);
  int e0 = rs[n], cnt = deg[n];
  float z = 0.f;
  f32x2 acc[8];
  #pragma unroll
  for (int j = 0; j < 8; j++){ acc[j].x = 0.f; acc[j].y = 0.f; }
  for (int base = 0; base < cnt; base += 4){
    int i0 = base + s, i1 = base + s + 2;
    bool p0 = i0 < cnt, p1 = i1 < cnt;
    // clamped, unconditional loads: inactive lanes re-read the last edge (L1 hit),
    // contribution zeroed via ew select. Keeps all 8 K/V loads in flight.
    u32 pk0 = epk[e0 + min(i0, cnt - 1)];
    u32 pk1 = epk[e0 + min(i1, cnt - 1)];
    const u16* kp0 = qkv + (size_t)(pk0 >> 2) * QKVW + 128 + ((pk0 & 3) << 7) + (h << 4);
    const u16* kp1 = qkv + (size_t)(pk1 >> 2) * QKVW + 128 + ((pk1 & 3) << 7) + (h << 4);
    uint4 ka0 = *(const uint4*)kp0, kb0 = *(const uint4*)(kp0 + 8);
    uint4 va0 = *(const uint4*)(kp0 + 512), vb0 = *(const uint4*)(kp0 + 520);
    uint4 ka1 = *(const uint4*)kp1, kb1 = *(const uint4*)(kp1 + 8);
    uint4 va1 = *(const uint4*)(kp1 + 512), vb1 = *(const uint4*)(kp1 + 520);
    f32x2 d0 = up2(ka0.x) * qv[0] + up2(ka0.y) * qv[1] + up2(ka0.z) * qv[2] + up2(ka0.w) * qv[3]
             + up2(kb0.x) * qv[4] + up2(kb0.y) * qv[5] + up2(kb0.z) * qv[6] + up2(kb0.w) * qv[7];
    f32x2 d1 = up2(ka1.x) * qv[0] + up2(ka1.y) * qv[1] + up2(ka1.z) * qv[2] + up2(ka1.w) * qv[3]
             + up2(kb1.x) * qv[4] + up2(kb1.y) * qv[5] + up2(kb1.z) * qv[6] + up2(kb1.w) * qv[7];
    float ew0 = p0 ? __expf(fminf((d0.x + d0.y) * 0.25f, 80.f)) : 0.f;
    float ew1 = p1 ? __expf(fminf((d1.x + d1.y) * 0.25f, 80.f)) : 0.f;
    z += ew0 + ew1;
    f32x2 w0v; w0v.x = ew0; w0v.y = ew0;
    f32x2 w1v; w1v.x = ew1; w1v.y = ew1;
    acc[0] += w0v * up2(va0.x); acc[1] += w0v * up2(va0.y);
    acc[2] += w0v * up2(va0.z); acc[3] += w0v * up2(va0.w);
    acc[4] += w0v * up2(vb0.x); acc[5] += w0v * up2(vb0.y);
    acc[6] += w0v * up2(vb0.z); acc[7] += w0v * up2(vb0.w);
    acc[0] += w1v * up2(va1.x); acc[1] += w1v * up2(va1.y);
    acc[2] += w1v * up2(va1.z); acc[3] += w1v * up2(va1.w);
    acc[4] += w1v * up2(vb1.x); acc[5] += w1v * up2(vb1.y);
    acc[6] += w1v * up2(vb1.z); acc[7] += w1v * up2(vb1.w);
  }
  // single butterfly round across the 2 slots (lane l <-> l^8)
  z += __shfl_xor(z, 8, 64);
  #pragma unroll
  for (int j = 0; j < 8; j++){
    acc[j].x += __shfl_xor(acc[j].x, 8, 64);
    acc[j].y += __shfl_xor(acc[j].y, 8, 64);
  }
  float inv = 1.f / (z + 1e-9f);
  float xv[8];
  if (s == 0){
    xv[0] = acc[0].x; xv[1] = acc[0].y; xv[2] = acc[1].x; xv[3] = acc[1].y;
    xv[4] = acc[2].x; xv[5] = acc[2].y; xv[6] = acc[3].x; xv[7] = acc[3].y;
  } else {
    xv[0] = acc[4].x; xv[1] = acc[4].y; xv[2] = acc[5].x; xv[3] = acc[5].y;
    xv[4] = acc[6].x; xv[5] = acc[6].y; xv[6] = acc[7].x; xv[7] = acc[7].y;
  }
  short8 ph, pl;
  #pragma unroll
  for (int k = 0; k < 8; k++){
    float y = xv[k] * inv;
    u16 hk = f2bf(y);
    ph[k] = (short)hk;
    pl[k] = (short)f2bf(y - bf2f(hk));
  }
  size_t pa = pkaddr(n >> 7, n & 127, (h << 4) + (s << 3));  // one aligned 8-chunk
  *(short8*)(agghi + pa) = ph;
  *(short8*)(agglo + pa) = pl;
}

// ---------- target readout ----------
__global__ __launch_bounds__(128) void readout(
    const float* __restrict__ feat, const float* __restrict__ twf,
    const int* __restrict__ key_ids, const int* __restrict__ invp,
    const int* __restrict__ tgt,
    float* __restrict__ outacc, void* dout, const int* __restrict__ flag, int blk)
{
  int t = threadIdx.x;
  int n = tgt[t];
  int key = key_ids[n];
  const float4* fr = (const float4*)(feat + (size_t)invp[n] * 128);
  const float4* wr = (const float4*)(twf + (size_t)((blk * 8 + key) << 7));
  float acc = 0.f;
  #pragma unroll
  for (int d = 0; d < 32; d++){
    float4 a = fr[d], b = wr[d];
    acc += a.x * b.x + a.y * b.y + a.z * b.z + a.w * b.w;
  }
  if (blk == 0){
    outacc[t] = 0.5f * acc;
  } else {
    float r = outacc[t] + 0.5f * acc;
    if (*flag) ((u16*)dout)[t] = f2bf(r);
    else       ((float*)dout)[t] = r;
  }
}

extern "C" void kernel_launch(void* const* d_in, const int* in_sizes, int n_in,
                              void* d_out, int out_size, void* d_ws, size_t ws_size,
                              hipStream_t stream)
{
  const void* emb = d_in[0];
  const void* qw  = d_in[1];
  const void* kw  = d_in[2];
  const void* vw  = d_in[3];
  const void* nw  = d_in[4];
  const void* tw  = d_in[5];
  const void* lg  = d_in[6];
  const void* lb  = d_in[7];
  const int* value_ids = (const int*)d_in[8];
  const int* key_ids   = (const int*)d_in[9];
  const int* srcp  = (const int*)d_in[10];
  const int* dstp  = (const int*)d_in[11];
  const int* etp   = (const int*)d_in[12];
  const int* tgt   = (const int*)d_in[13];

  char* p = (char*)d_ws;
  auto carve = [&](size_t bytes)->char*{
    char* r = p; p += (bytes + 255) & ~(size_t)255; return r;
  };
  int*   flag    = (int*)  carve(4);
  float* featp   = (float*)carve((size_t)NPAD * 128 * 4);
  u16*   feathi  = (u16*)  carve((size_t)NPAD * 128 * 2);
  u16*   featlo  = (u16*)  carve((size_t)NPAD * 128 * 2);
  u16*   qwc     = (u16*)  carve((size_t)2 * 1024 * 128 * 2);
  u16*   kvw     = (u16*)  carve((size_t)2 * 1024 * 128 * 2);
  u16*   nwc     = (u16*)  carve((size_t)2 * 1024 * 128 * 2);
  float* twf     = (float*)carve((size_t)2048 * 4);
  float* gbf     = (float*)carve((size_t)512 * 4);
  int*   blkcnt  = (int*)  carve((size_t)8 * NBLK * 4);
  int*   kbase   = (int*)  carve((size_t)8 * NBLK * 4);
  int*   tile_key= (int*)  carve(NTILES * 4);
  int*   perm    = (int*)  carve((size_t)NPAD * 4);
  int*   invperm = (int*)  carve((size_t)N_NODES * 4);
  int*   deg     = (int*)  carve((size_t)NPAD * 4);
  int*   rsx     = (int*)  carve((size_t)NPAD * 4);
  int*   cur     = (int*)  carve((size_t)NPAD * 4);
  u32*   epk     = (u32*)  carve((size_t)N_EDGES * 4);
  u16*   qkvbuf  = (u16*)  carve((size_t)NPAD * QKVW * 2);
  u16*   agghi   = (u16*)  carve((size_t)NPAD * 128 * 2);
  u16*   agglo   = (u16*)  carve((size_t)NPAD * 128 * 2);
  float* outacc  = (float*)carve((size_t)N_TARGETS * 4);
  (void)ws_size; (void)n_in; (void)in_sizes; (void)out_size;

  detect_dtype<<<1, 256, 0, stream>>>((const u16*)emb, flag);

  // fused weight/param conversion + perm zeroing (replaces memset dispatch)
  cvt_all<<<3282, 256, 0, stream>>>(qw, nw, kw, vw, tw, lg, lb,
                                    qwc, nwc, kvw, twf, gbf, perm, flag);

  // deterministic key-bucket counting sort
  khist_blk<<<NBLK, 256, 0, stream>>>(key_ids, blkcnt);
  kscan2<<<1, 64, 0, stream>>>(blkcnt, kbase, tile_key);
  scatter_perm2<<<NBLK, 256, 0, stream>>>(key_ids, kbase, perm, invperm);

  gather_feat<<<(NPAD * 128) / 256, 256, 0, stream>>>(emb, value_ids, perm, flag,
                                                      featp, feathi, featlo, deg);

  // CSR in perm space; canonicalize per-node edge order for determinism
  const int eg = (N_EDGES + 255) / 256;
  hist_dst<<<eg, 256, 0, stream>>>(dstp, invperm, deg);
  scan_deg<<<1, 1024, 0, stream>>>(deg, rsx, cur);
  scatter_edges<<<eg, 256, 0, stream>>>(srcp, dstp, etp, invperm, cur, epk);
  sort_csr<<<(NPAD + 255) / 256, 256, 0, stream>>>(rsx, deg, epk);

  for (int b = 0; b < NUM_BLOCKS; b++){
    gemm_qkv<<<3600, 256, 0, stream>>>(feathi, featlo,
                                       qwc + (size_t)b * 1024 * 128,
                                       kvw + (size_t)b * 1024 * 128,
                                       tile_key, qkvbuf);
    edge_attn<<<NPAD / 16, 256, 0, stream>>>(qkvbuf, rsx, deg, epk, agghi, agglo);
    gemm_h_ln<<<NPAD / 64, 256, 0, stream>>>(agghi, agglo,
                                             nwc + (size_t)b * 1024 * 128,
                                             tile_key, gbf, featp, feathi, featlo, b);
    readout<<<1, 128, 0, stream>>>(featp, twf, key_ids, invperm, tgt, outacc, d_out, flag, b);
  }
}

// Round 6
// 460.810 us; speedup vs baseline: 1.0917x; 1.0503x over previous
//
#include <hip/hip_runtime.h>
#include <hip/hip_bf16.h>

#define N_NODES   50000
#define N_EDGES   500000
#define NHEAD     8
#define NUM_KEYS  8
#define NUM_ETYPES 4
#define NUM_BLOCKS 2
#define N_TARGETS 128
#define NPAD      51200   // 400 tiles * 128
#define NTILES    400
#define NBLK      196     // ceil(N_NODES/256)
#define NSBLK     200     // NPAD/256 scan blocks
#define LDW       136     // u16 LDS stride (16B-aligned rows)
#define LDWF      132     // f32 LDS stride
#define QKVW      1152    // unified row: [q 128 | k 512 | v 512]
#define SCAP      45      // LDS sort scratch per thread (odd stride -> conflict-light)

typedef unsigned short u16;
typedef unsigned int   u32;
typedef __attribute__((ext_vector_type(8))) short short8;
typedef __attribute__((ext_vector_type(4))) short short4v;
typedef __attribute__((ext_vector_type(4))) float floatx4;
typedef __attribute__((ext_vector_type(2))) float f32x2;

// packed (fragment-major) address within a 128x128 u16 tile:
// elem(row r, col c) -> (c>>3)*1024 + r*8 + (c&7).
__device__ __forceinline__ size_t pkaddr(int tile, int r, int c){
  return (size_t)tile * 16384 + ((c >> 3) << 10) + (r << 3) + (c & 7);
}

// ---------- bf16 helpers ----------
__device__ __forceinline__ float bflo(u32 u)  { return __uint_as_float(u << 16); }
__device__ __forceinline__ float bfhi(u32 u)  { return __uint_as_float(u & 0xffff0000u); }
__device__ __forceinline__ float bf2f(u16 u)  { return __uint_as_float(((u32)u) << 16); }
__device__ __forceinline__ u16   f2bf(float f){
  u32 u = __float_as_uint(f);
  u += 0x7fffu + ((u >> 16) & 1u);
  return (u16)(u >> 16);
}
__device__ __forceinline__ f32x2 up2(u32 u){
  f32x2 r; r.x = bflo(u); r.y = bfhi(u); return r;
}

// ---------- dtype detector ----------
__global__ void detect_dtype(const u16* raw, int* flag){
  __shared__ int cnt;
  if (threadIdx.x == 0) cnt = 0;
  __syncthreads();
  int sane = 0;
  #pragma unroll
  for (int k = 0; k < 4; k++){
    u16 u = raw[threadIdx.x * 4 + k];
    int e = (u >> 7) & 0xff;
    if (e >= 100 && e <= 145) sane++;
  }
  atomicAdd(&cnt, sane);
  __syncthreads();
  if (threadIdx.x == 0) *flag = (cnt >= 870) ? 1 : 0;
}

// ---------- fused weight conversion (+ perm zeroing folded in) ----------
// blocks 0..1023: qw -> qwc (packed); 1024..2047: nw -> nwc (packed);
// 2048..3071: kw/vw -> kvw (packed, [blk][k|v]); 3072..3079: tw -> twf (f32);
// 3080: ln_gamma; 3081: ln_beta; 3082..3281: zero perm (integer-only, replaces
// the standalone hipMemsetAsync dispatch).
__global__ void cvt_all(const void* qw, const void* nw, const void* kw, const void* vw,
                        const void* tw, const void* lgp, const void* lbp,
                        u16* __restrict__ qwc, u16* __restrict__ nwc, u16* __restrict__ kvw,
                        float* __restrict__ twf, float* __restrict__ gbf,
                        int* __restrict__ perm,
                        const int* __restrict__ flag){
  int b = blockIdx.x, t = threadIdx.x;
  if (b >= 3082){
    perm[((b - 3082) << 8) + t] = 0;
    return;
  }
  int fl = *flag;
  if (b < 2048){
    const void* src = (b < 1024) ? qw : nw;
    u16* dst = (b < 1024) ? qwc : nwc;
    int i = ((b & 1023) << 8) + t;
    u16 v = fl ? ((const u16*)src)[i] : f2bf(((const float*)src)[i]);
    int mat = i >> 14, rem = i & 16383;
    dst[pkaddr(mat, rem >> 7, rem & 127)] = v;
  } else if (b < 3072){
    int r = b - 2048;
    int blk = r >> 9, half = (r >> 8) & 1;
    int i = ((r & 255) << 8) + t;                  // 0..65535 within (blk,half)
    const void* src = half ? vw : kw;
    size_t soff = (size_t)blk * 65536 + i;
    u16 v = fl ? ((const u16*)src)[soff] : f2bf(((const float*)src)[soff]);
    int mat = i >> 14, rem = i & 16383;
    kvw[(size_t)blk * 131072 + (size_t)half * 65536 + pkaddr(mat, rem >> 7, rem & 127)] = v;
  } else if (b < 3080){
    int i = ((b - 3072) << 8) + t;
    twf[i] = fl ? bf2f(((const u16*)tw)[i]) : ((const float*)tw)[i];
  } else if (b == 3080){
    gbf[t] = fl ? bf2f(((const u16*)lgp)[t]) : ((const float*)lgp)[t];
  } else {
    gbf[256 + t] = fl ? bf2f(((const u16*)lbp)[t]) : ((const float*)lbp)[t];
  }
}

// ---------- contention-free, deterministic key-bucket counting sort ----------
__global__ void khist_blk(const int* __restrict__ key_ids, int* __restrict__ blkcnt){
  __shared__ int c[8];
  int t = threadIdx.x, b = blockIdx.x;
  if (t < 8) c[t] = 0;
  __syncthreads();
  int n = b * 256 + t;
  if (n < N_NODES) atomicAdd(&c[key_ids[n]], 1);
  __syncthreads();
  if (t < 8) blkcnt[t * NBLK + b] = c[t];
}
__global__ void kscan2(const int* __restrict__ blkcnt, int* __restrict__ base,
                       int* __restrict__ tile_key){
  __shared__ int po[8];
  __shared__ int tot[8];
  int t = threadIdx.x;  // 64 threads
  if (t < 8){
    int s = 0;
    for (int b = 0; b < NBLK; b++) s += blkcnt[t * NBLK + b];
    tot[t] = s;
  }
  __syncthreads();
  if (t == 0){
    int off = 0;
    for (int k = 0; k < 8; k++){ po[k] = off; off += ((tot[k] + 127) >> 7) << 7; }
  }
  __syncthreads();
  if (t < 8){
    int run = po[t];
    for (int b = 0; b < NBLK; b++){ base[t * NBLK + b] = run; run += blkcnt[t * NBLK + b]; }
  }
  for (int tt = t; tt < NTILES; tt += 64){
    int row = tt << 7, k = 7;
    for (int kk = 1; kk < 8; kk++)
      if (row < po[kk]){ k = kk - 1; break; }
    tile_key[tt] = k;
  }
}
__global__ void scatter_perm2(const int* __restrict__ key_ids, const int* __restrict__ base,
                              int* __restrict__ perm, int* __restrict__ invperm){
  __shared__ unsigned char keyarr[256];
  int t = threadIdx.x, b = blockIdx.x;
  int n = b * 256 + t;
  int key = (n < N_NODES) ? key_ids[n] : 8;
  keyarr[t] = (unsigned char)key;
  __syncthreads();
  if (n >= N_NODES) return;
  int rank = 0;
  for (int j = 0; j < t; j++) rank += (keyarr[j] == (unsigned char)key);
  int pos = base[key * NBLK + b] + rank;
  perm[pos] = n;
  invperm[n] = pos;
}

// ---------- feat gather: f32 linear + hi/lo bf16 packed (also zeroes deg) ----------
__global__ void gather_feat(const void* emb_raw, const int* __restrict__ vid,
                            const int* __restrict__ perm, const int* __restrict__ flag,
                            float* __restrict__ feat, u16* __restrict__ fhi,
                            u16* __restrict__ flo, int* __restrict__ deg){
  int i = blockIdx.x * 256 + threadIdx.x;          // NPAD*128 exact
  int n = i >> 7, d = i & 127;
  if (d == 0) deg[n] = 0;
  int e = (vid[perm[n]] << 7) + d;
  float v = (*flag) ? bf2f(((const u16*)emb_raw)[e]) : ((const float*)emb_raw)[e];
  feat[i] = v;
  u16 h = f2bf(v);
  size_t pa = pkaddr(n >> 7, n & 127, d);
  fhi[pa] = h;
  flo[pa] = f2bf(v - bf2f(h));
}

// ---------- CSR build (perm space) ----------
__global__ void hist_dst(const int* __restrict__ dst, const int* __restrict__ invp,
                         int* __restrict__ deg){
  int e = blockIdx.x * 256 + threadIdx.x;
  if (e < N_EDGES) atomicAdd(&deg[invp[dst[e]]], 1);
}
// parallel two-level exclusive scan of deg -> rs/cur (replaces the single-block
// scan_deg, which serialized ~600KB of traffic through one CU: est ~40-60us).
// Bit-identical result: rs[n] = sum(deg[0..n)). All-integer, deterministic.
__global__ void dsum_blk(const int* __restrict__ deg, int* __restrict__ dsum){
  __shared__ int s[256];
  int t = threadIdx.x, b = blockIdx.x;
  s[t] = deg[b * 256 + t];
  __syncthreads();
  for (int off = 128; off > 0; off >>= 1){
    if (t < off) s[t] += s[t + off];
    __syncthreads();
  }
  if (t == 0) dsum[b] = s[0];
}
__global__ void dscan_write(const int* __restrict__ deg, const int* __restrict__ dsum,
                            int* __restrict__ rs, int* __restrict__ cur){
  __shared__ int sb[256];
  __shared__ int sd[256];
  int t = threadIdx.x, b = blockIdx.x;
  // base = sum of dsum[0..b)  (b < NSBLK=200 < 256)
  sb[t] = (t < b) ? dsum[t] : 0;
  __syncthreads();
  for (int off = 128; off > 0; off >>= 1){
    if (t < off) sb[t] += sb[t + off];
    __syncthreads();
  }
  int base = sb[0];
  int n = b * 256 + t;
  int v = deg[n];
  sd[t] = v;
  __syncthreads();
  // inclusive Hillis-Steele scan over the block's 256 degrees
  for (int off = 1; off < 256; off <<= 1){
    int x = (t >= off) ? sd[t - off] : 0;
    __syncthreads();
    sd[t] += x;
    __syncthreads();
  }
  int r = base + sd[t] - v;   // exclusive prefix
  rs[n] = r;
  cur[n] = r;
}
__global__ void scatter_edges(const int* __restrict__ src, const int* __restrict__ dst,
                              const int* __restrict__ et, const int* __restrict__ invp,
                              int* __restrict__ cur, u32* __restrict__ epk){
  int e = blockIdx.x * 256 + threadIdx.x;
  if (e >= N_EDGES) return;
  int pos = atomicAdd(&cur[invp[dst[e]]], 1);
  epk[pos] = ((u32)invp[src[e]] << 2) | (u32)et[e];
}
// canonicalize within-node edge order (determinism). LDS-cached insertion sort.
__global__ __launch_bounds__(256) void sort_csr(const int* __restrict__ rs,
                                                const int* __restrict__ deg,
                                                u32* __restrict__ epk){
  __shared__ u32 buf[256 * SCAP];
  int t = threadIdx.x;
  int n = blockIdx.x * 256 + t;
  if (n >= NPAD) return;
  int s = rs[n], c = deg[n];
  if (c <= 1) return;
  if (c <= SCAP){
    u32* b = buf + t * SCAP;
    for (int i = 0; i < c; i++) b[i] = epk[s + i];
    for (int i = 1; i < c; i++){
      u32 v = b[i];
      int j = i - 1;
      while (j >= 0 && b[j] > v){ b[j + 1] = b[j]; j--; }
      b[j + 1] = v;
    }
    for (int i = 0; i < c; i++) epk[s + i] = b[i];
  } else {
    for (int i = 1; i < c; i++){
      u32 v = epk[s + i];
      int j = i - 1;
      while (j >= 0 && epk[s + j] > v){ epk[s + j + 1] = epk[s + j]; j--; }
      epk[s + j + 1] = v;
    }
  }
}

// ---------- unified q+kv MFMA GEMM, packed operands, XCD-affine swizzle ----------
__global__ __launch_bounds__(256) void gemm_qkv(
    const u16* __restrict__ Ahi, const u16* __restrict__ Alo,
    const u16* __restrict__ Qw, const u16* __restrict__ KVw,
    const int* __restrict__ tkey, u16* __restrict__ C)
{
  __shared__ u16 sc[128 * LDW];
  int id = blockIdx.x;
  int xcd = id & 7, wi = id >> 3;        // wi in [0,450)
  int cy = xcd * 50 + wi / 9;            // row tile
  int cx = wi % 9;                       // column tile: 0=q, 1..8=kv
  int m0 = cy * 128;
  const u16* Bte = (cx == 0) ? (Qw + (size_t)tkey[cy] * 16384)
                             : (KVw + (size_t)(cx - 1) * 16384);
  const u16* Ath = Ahi + (size_t)cy * 16384;
  const u16* Atl = Alo + (size_t)cy * 16384;
  int w = threadIdx.x >> 6, l = threadIdx.x & 63;
  int wm = (w & 1) * 64, wn = (w >> 1) * 64;
  int lr = l & 15, lg = l >> 4;
  floatx4 acc[4][4] = {};
  #pragma unroll
  for (int kk = 0; kk < 4; kk++){
    int cc10 = (kk * 4 + lg) << 10;      // chunk base in packed tile
    short8 ah[4], al[4], bfr[4];
    #pragma unroll
    for (int i = 0; i < 4; i++){
      int off = cc10 + ((wm + i * 16 + lr) << 3);
      ah[i] = *(const short8*)(Ath + off);
      al[i] = *(const short8*)(Atl + off);
    }
    #pragma unroll
    for (int j = 0; j < 4; j++)
      bfr[j] = *(const short8*)(Bte + cc10 + ((wn + j * 16 + lr) << 3));
    #pragma unroll
    for (int i = 0; i < 4; i++)
      #pragma unroll
      for (int j = 0; j < 4; j++){
        acc[i][j] = __builtin_amdgcn_mfma_f32_16x16x32_bf16(ah[i], bfr[j], acc[i][j], 0, 0, 0);
        acc[i][j] = __builtin_amdgcn_mfma_f32_16x16x32_bf16(al[i], bfr[j], acc[i][j], 0, 0, 0);
      }
  }
  #pragma unroll
  for (int i = 0; i < 4; i++)
    #pragma unroll
    for (int j = 0; j < 4; j++)
      #pragma unroll
      for (int r = 0; r < 4; r++)
        sc[(wm + i * 16 + lg * 4 + r) * LDW + wn + j * 16 + lr] = f2bf(acc[i][j][r]);
  __syncthreads();
  int tr = threadIdx.x >> 4, tc = (threadIdx.x & 15) * 8;
  int cbase = cx * 128;   // q at cols 0..127, kv at 128..1151
  #pragma unroll
  for (int it = 0; it < 8; it++){
    int row = tr + it * 16;
    short8 vv = *(const short8*)(sc + row * LDW + tc);
    *(short8*)(C + (size_t)(m0 + row) * QKVW + cbase + tc) = vv;
  }
}

// ---------- fused node GEMM (packed hi/lo A) + relu + f32 LN + residual ----------
__global__ __launch_bounds__(256) void gemm_h_ln(
    const u16* __restrict__ Ahi, const u16* __restrict__ Alo,
    const u16* __restrict__ Bt, const int* __restrict__ tkey,
    const float* __restrict__ gbf,
    float* __restrict__ feat, u16* __restrict__ fhi, u16* __restrict__ flo, int blk)
{
  __shared__ float scf[64 * LDWF];
  int m0 = blockIdx.x * 64;
  int tile = blockIdx.x >> 1, rbase = (blockIdx.x & 1) * 64;
  const u16* Bte = Bt + (size_t)tkey[tile] * 16384;
  const u16* Ath = Ahi + (size_t)tile * 16384;
  const u16* Atl = Alo + (size_t)tile * 16384;
  int w = threadIdx.x >> 6, l = threadIdx.x & 63;
  int wn = w * 32;
  int lr = l & 15, lg = l >> 4;
  floatx4 acc[4][2] = {};
  #pragma unroll
  for (int kk = 0; kk < 4; kk++){
    int cc10 = (kk * 4 + lg) << 10;
    short8 ah[4], al[4], bfr[2];
    #pragma unroll
    for (int i = 0; i < 4; i++){
      int off = cc10 + ((rbase + i * 16 + lr) << 3);
      ah[i] = *(const short8*)(Ath + off);
      al[i] = *(const short8*)(Atl + off);
    }
    #pragma unroll
    for (int j = 0; j < 2; j++)
      bfr[j] = *(const short8*)(Bte + cc10 + ((wn + j * 16 + lr) << 3));
    #pragma unroll
    for (int i = 0; i < 4; i++)
      #pragma unroll
      for (int j = 0; j < 2; j++){
        acc[i][j] = __builtin_amdgcn_mfma_f32_16x16x32_bf16(ah[i], bfr[j], acc[i][j], 0, 0, 0);
        acc[i][j] = __builtin_amdgcn_mfma_f32_16x16x32_bf16(al[i], bfr[j], acc[i][j], 0, 0, 0);
      }
  }
  #pragma unroll
  for (int i = 0; i < 4; i++)
    #pragma unroll
    for (int j = 0; j < 2; j++)
      #pragma unroll
      for (int r = 0; r < 4; r++)
        scf[(i * 16 + lg * 4 + r) * LDWF + wn + j * 16 + lr] = acc[i][j][r];
  __syncthreads();
  int r = threadIdx.x >> 2, q4 = (threadIdx.x & 3) * 32;
  const float* srow = scf + r * LDWF + q4;
  float s1 = 0.f, s2 = 0.f;
  #pragma unroll
  for (int c = 0; c < 32; c++){
    float v = fmaxf(srow[c], 0.f);
    s1 += v; s2 += v * v;
  }
  s1 += __shfl_xor(s1, 1, 64); s1 += __shfl_xor(s1, 2, 64);
  s2 += __shfl_xor(s2, 1, 64); s2 += __shfl_xor(s2, 2, 64);
  float mu = s1 * (1.f / 128.f);
  float var = s2 * (1.f / 128.f) - mu * mu;
  float rstd = rsqrtf(var + 1e-5f);
  int n = m0 + r;
  int ntile = n >> 7, nr = n & 127;
  float* fr = feat + (size_t)n * 128 + q4;
  const float* gp = gbf + (blk << 7) + q4;
  #pragma unroll
  for (int c = 0; c < 32; c += 4){
    float4 fo = *(float4*)(fr + c);
    float y0 = (fmaxf(srow[c+0], 0.f) - mu) * rstd * gp[c+0] + gp[256 + c + 0] + fo.x;
    float y1 = (fmaxf(srow[c+1], 0.f) - mu) * rstd * gp[c+1] + gp[256 + c + 1] + fo.y;
    float y2 = (fmaxf(srow[c+2], 0.f) - mu) * rstd * gp[c+2] + gp[256 + c + 2] + fo.z;
    float y3 = (fmaxf(srow[c+3], 0.f) - mu) * rstd * gp[c+3] + gp[256 + c + 3] + fo.w;
    *(float4*)(fr + c) = make_float4(y0, y1, y2, y3);
    u16 h0 = f2bf(y0), h1 = f2bf(y1), h2 = f2bf(y2), h3 = f2bf(y3);
    size_t pa = pkaddr(ntile, nr, q4 + c);   // q4+c mult of 4 -> within one 8-chunk
    short4v ph; ph.x = (short)h0; ph.y = (short)h1; ph.z = (short)h2; ph.w = (short)h3;
    *(short4v*)(fhi + pa) = ph;
    short4v pl;
    pl.x = (short)f2bf(y0 - bf2f(h0)); pl.y = (short)f2bf(y1 - bf2f(h1));
    pl.z = (short)f2bf(y2 - bf2f(h2)); pl.w = (short)f2bf(y3 - bf2f(h3));
    *(short4v*)(flo + pa) = pl;
  }
}

// ---------- single-pass edge attention (16 lanes/node: 8 heads x 2 slots) ----------
// VERIFIED v2 structure — do not restructure (two equivalent-looking rewrites
// failed verification; see session journal).
__global__ __launch_bounds__(256) void edge_attn(
    const u16* __restrict__ qkv,
    const int* __restrict__ rs, const int* __restrict__ deg,
    const u32* __restrict__ epk, u16* __restrict__ agghi, u16* __restrict__ agglo)
{
  int n = blockIdx.x * 16 + (threadIdx.x >> 4);
  int l = threadIdx.x & 15;
  int h = l & 7, s = l >> 3;               // s in {0,1}
  const u16* qp = qkv + (size_t)n * QKVW + (h << 4);
  uint4 q0 = *(const uint4*)qp, q1 = *(const uint4*)(qp + 8);
  f32x2 qv[8];
  qv[0] = up2(q0.x); qv[1] = up2(q0.y); qv[2] = up2(q0.z); qv[3] = up2(q0.w);
  qv[4] = up2(q1.x); qv[5] = up2(q1.y); qv[6] = up2(q1.z); qv[7] = up2(q1.w);
  int e0 = rs[n], cnt = deg[n];
  float z = 0.f;
  f32x2 acc[8];
  #pragma unroll
  for (int j = 0; j < 8; j++){ acc[j].x = 0.f; acc[j].y = 0.f; }
  for (int base = 0; base < cnt; base += 4){
    int i0 = base + s, i1 = base + s + 2;
    bool p0 = i0 < cnt, p1 = i1 < cnt;
    // clamped, unconditional loads: inactive lanes re-read the last edge (L1 hit),
    // contribution zeroed via ew select. Keeps all 8 K/V loads in flight.
    u32 pk0 = epk[e0 + min(i0, cnt - 1)];
    u32 pk1 = epk[e0 + min(i1, cnt - 1)];
    const u16* kp0 = qkv + (size_t)(pk0 >> 2) * QKVW + 128 + ((pk0 & 3) << 7) + (h << 4);
    const u16* kp1 = qkv + (size_t)(pk1 >> 2) * QKVW + 128 + ((pk1 & 3) << 7) + (h << 4);
    uint4 ka0 = *(const uint4*)kp0, kb0 = *(const uint4*)(kp0 + 8);
    uint4 va0 = *(const uint4*)(kp0 + 512), vb0 = *(const uint4*)(kp0 + 520);
    uint4 ka1 = *(const uint4*)kp1, kb1 = *(const uint4*)(kp1 + 8);
    uint4 va1 = *(const uint4*)(kp1 + 512), vb1 = *(const uint4*)(kp1 + 520);
    f32x2 d0 = up2(ka0.x) * qv[0] + up2(ka0.y) * qv[1] + up2(ka0.z) * qv[2] + up2(ka0.w) * qv[3]
             + up2(kb0.x) * qv[4] + up2(kb0.y) * qv[5] + up2(kb0.z) * qv[6] + up2(kb0.w) * qv[7];
    f32x2 d1 = up2(ka1.x) * qv[0] + up2(ka1.y) * qv[1] + up2(ka1.z) * qv[2] + up2(ka1.w) * qv[3]
             + up2(kb1.x) * qv[4] + up2(kb1.y) * qv[5] + up2(kb1.z) * qv[6] + up2(kb1.w) * qv[7];
    float ew0 = p0 ? __expf(fminf((d0.x + d0.y) * 0.25f, 80.f)) : 0.f;
    float ew1 = p1 ? __expf(fminf((d1.x + d1.y) * 0.25f, 80.f)) : 0.f;
    z += ew0 + ew1;
    f32x2 w0v; w0v.x = ew0; w0v.y = ew0;
    f32x2 w1v; w1v.x = ew1; w1v.y = ew1;
    acc[0] += w0v * up2(va0.x); acc[1] += w0v * up2(va0.y);
    acc[2] += w0v * up2(va0.z); acc[3] += w0v * up2(va0.w);
    acc[4] += w0v * up2(vb0.x); acc[5] += w0v * up2(vb0.y);
    acc[6] += w0v * up2(vb0.z); acc[7] += w0v * up2(vb0.w);
    acc[0] += w1v * up2(va1.x); acc[1] += w1v * up2(va1.y);
    acc[2] += w1v * up2(va1.z); acc[3] += w1v * up2(va1.w);
    acc[4] += w1v * up2(vb1.x); acc[5] += w1v * up2(vb1.y);
    acc[6] += w1v * up2(vb1.z); acc[7] += w1v * up2(vb1.w);
  }
  // single butterfly round across the 2 slots (lane l <-> l^8)
  z += __shfl_xor(z, 8, 64);
  #pragma unroll
  for (int j = 0; j < 8; j++){
    acc[j].x += __shfl_xor(acc[j].x, 8, 64);
    acc[j].y += __shfl_xor(acc[j].y, 8, 64);
  }
  float inv = 1.f / (z + 1e-9f);
  float xv[8];
  if (s == 0){
    xv[0] = acc[0].x; xv[1] = acc[0].y; xv[2] = acc[1].x; xv[3] = acc[1].y;
    xv[4] = acc[2].x; xv[5] = acc[2].y; xv[6] = acc[3].x; xv[7] = acc[3].y;
  } else {
    xv[0] = acc[4].x; xv[1] = acc[4].y; xv[2] = acc[5].x; xv[3] = acc[5].y;
    xv[4] = acc[6].x; xv[5] = acc[6].y; xv[6] = acc[7].x; xv[7] = acc[7].y;
  }
  short8 ph, pl;
  #pragma unroll
  for (int k = 0; k < 8; k++){
    float y = xv[k] * inv;
    u16 hk = f2bf(y);
    ph[k] = (short)hk;
    pl[k] = (short)f2bf(y - bf2f(hk));
  }
  size_t pa = pkaddr(n >> 7, n & 127, (h << 4) + (s << 3));  // one aligned 8-chunk
  *(short8*)(agghi + pa) = ph;
  *(short8*)(agglo + pa) = pl;
}

// ---------- target readout ----------
__global__ __launch_bounds__(128) void readout(
    const float* __restrict__ feat, const float* __restrict__ twf,
    const int* __restrict__ key_ids, const int* __restrict__ invp,
    const int* __restrict__ tgt,
    float* __restrict__ outacc, void* dout, const int* __restrict__ flag, int blk)
{
  int t = threadIdx.x;
  int n = tgt[t];
  int key = key_ids[n];
  const float4* fr = (const float4*)(feat + (size_t)invp[n] * 128);
  const float4* wr = (const float4*)(twf + (size_t)((blk * 8 + key) << 7));
  float acc = 0.f;
  #pragma unroll
  for (int d = 0; d < 32; d++){
    float4 a = fr[d], b = wr[d];
    acc += a.x * b.x + a.y * b.y + a.z * b.z + a.w * b.w;
  }
  if (blk == 0){
    outacc[t] = 0.5f * acc;
  } else {
    float r = outacc[t] + 0.5f * acc;
    if (*flag) ((u16*)dout)[t] = f2bf(r);
    else       ((float*)dout)[t] = r;
  }
}

extern "C" void kernel_launch(void* const* d_in, const int* in_sizes, int n_in,
                              void* d_out, int out_size, void* d_ws, size_t ws_size,
                              hipStream_t stream)
{
  const void* emb = d_in[0];
  const void* qw  = d_in[1];
  const void* kw  = d_in[2];
  const void* vw  = d_in[3];
  const void* nw  = d_in[4];
  const void* tw  = d_in[5];
  const void* lg  = d_in[6];
  const void* lb  = d_in[7];
  const int* value_ids = (const int*)d_in[8];
  const int* key_ids   = (const int*)d_in[9];
  const int* srcp  = (const int*)d_in[10];
  const int* dstp  = (const int*)d_in[11];
  const int* etp   = (const int*)d_in[12];
  const int* tgt   = (const int*)d_in[13];

  char* p = (char*)d_ws;
  auto carve = [&](size_t bytes)->char*{
    char* r = p; p += (bytes + 255) & ~(size_t)255; return r;
  };
  int*   flag    = (int*)  carve(4);
  float* featp   = (float*)carve((size_t)NPAD * 128 * 4);
  u16*   feathi  = (u16*)  carve((size_t)NPAD * 128 * 2);
  u16*   featlo  = (u16*)  carve((size_t)NPAD * 128 * 2);
  u16*   qwc     = (u16*)  carve((size_t)2 * 1024 * 128 * 2);
  u16*   kvw     = (u16*)  carve((size_t)2 * 1024 * 128 * 2);
  u16*   nwc     = (u16*)  carve((size_t)2 * 1024 * 128 * 2);
  float* twf     = (float*)carve((size_t)2048 * 4);
  float* gbf     = (float*)carve((size_t)512 * 4);
  int*   blkcnt  = (int*)  carve((size_t)8 * NBLK * 4);
  int*   kbase   = (int*)  carve((size_t)8 * NBLK * 4);
  int*   tile_key= (int*)  carve(NTILES * 4);
  int*   perm    = (int*)  carve((size_t)NPAD * 4);
  int*   invperm = (int*)  carve((size_t)N_NODES * 4);
  int*   deg     = (int*)  carve((size_t)NPAD * 4);
  int*   rsx     = (int*)  carve((size_t)NPAD * 4);
  int*   cur     = (int*)  carve((size_t)NPAD * 4);
  int*   dsum    = (int*)  carve((size_t)NSBLK * 4);
  u32*   epk     = (u32*)  carve((size_t)N_EDGES * 4);
  u16*   qkvbuf  = (u16*)  carve((size_t)NPAD * QKVW * 2);
  u16*   agghi   = (u16*)  carve((size_t)NPAD * 128 * 2);
  u16*   agglo   = (u16*)  carve((size_t)NPAD * 128 * 2);
  float* outacc  = (float*)carve((size_t)N_TARGETS * 4);
  (void)ws_size; (void)n_in; (void)in_sizes; (void)out_size;

  detect_dtype<<<1, 256, 0, stream>>>((const u16*)emb, flag);

  // fused weight/param conversion + perm zeroing (replaces memset dispatch)
  cvt_all<<<3282, 256, 0, stream>>>(qw, nw, kw, vw, tw, lg, lb,
                                    qwc, nwc, kvw, twf, gbf, perm, flag);

  // deterministic key-bucket counting sort
  khist_blk<<<NBLK, 256, 0, stream>>>(key_ids, blkcnt);
  kscan2<<<1, 64, 0, stream>>>(blkcnt, kbase, tile_key);
  scatter_perm2<<<NBLK, 256, 0, stream>>>(key_ids, kbase, perm, invperm);

  gather_feat<<<(NPAD * 128) / 256, 256, 0, stream>>>(emb, value_ids, perm, flag,
                                                      featp, feathi, featlo, deg);

  // CSR in perm space; canonicalize per-node edge order for determinism
  const int eg = (N_EDGES + 255) / 256;
  hist_dst<<<eg, 256, 0, stream>>>(dstp, invperm, deg);
  dsum_blk<<<NSBLK, 256, 0, stream>>>(deg, dsum);
  dscan_write<<<NSBLK, 256, 0, stream>>>(deg, dsum, rsx, cur);
  scatter_edges<<<eg, 256, 0, stream>>>(srcp, dstp, etp, invperm, cur, epk);
  sort_csr<<<(NPAD + 255) / 256, 256, 0, stream>>>(rsx, deg, epk);

  for (int b = 0; b < NUM_BLOCKS; b++){
    gemm_qkv<<<3600, 256, 0, stream>>>(feathi, featlo,
                                       qwc + (size_t)b * 1024 * 128,
                                       kvw + (size_t)b * 1024 * 128,
                                       tile_key, qkvbuf);
    edge_attn<<<NPAD / 16, 256, 0, stream>>>(qkvbuf, rsx, deg, epk, agghi, agglo);
    gemm_h_ln<<<NPAD / 64, 256, 0, stream>>>(agghi, agglo,
                                             nwc + (size_t)b * 1024 * 128,
                                             tile_key, gbf, featp, feathi, featlo, b);
    readout<<<1, 128, 0, stream>>>(featp, twf, key_ids, invperm, tgt, outacc, d_out, flag, b);
  }
}

// Round 9
// 456.941 us; speedup vs baseline: 1.1009x; 1.0085x over previous
//
#include <hip/hip_runtime.h>
#include <hip/hip_bf16.h>

#define N_NODES   50000
#define N_EDGES   500000
#define NHEAD     8
#define NUM_KEYS  8
#define NUM_ETYPES 4
#define NUM_BLOCKS 2
#define N_TARGETS 128
#define NPAD      51200   // 400 tiles * 128
#define NTILES    400
#define NBLK      196     // ceil(N_NODES/256)
#define NSBLK     200     // NPAD/256 scan blocks
#define LDW       136     // u16 LDS stride (16B-aligned rows)
#define LDWF      132     // f32 LDS stride
#define QKVW      1152    // unified row: [q 128 | k 512 | v 512]
#define SCAP      45      // LDS sort scratch per thread (odd stride -> conflict-light)

typedef unsigned short u16;
typedef unsigned int   u32;
typedef __attribute__((ext_vector_type(8))) short short8;
typedef __attribute__((ext_vector_type(4))) short short4v;
typedef __attribute__((ext_vector_type(4))) float floatx4;
typedef __attribute__((ext_vector_type(2))) float f32x2;

// packed (fragment-major) address within a 128x128 u16 tile:
// elem(row r, col c) -> (c>>3)*1024 + r*8 + (c&7).
__device__ __forceinline__ size_t pkaddr(int tile, int r, int c){
  return (size_t)tile * 16384 + ((c >> 3) << 10) + (r << 3) + (c & 7);
}

// ---------- bf16 helpers ----------
__device__ __forceinline__ float bflo(u32 u)  { return __uint_as_float(u << 16); }
__device__ __forceinline__ float bfhi(u32 u)  { return __uint_as_float(u & 0xffff0000u); }
__device__ __forceinline__ float bf2f(u16 u)  { return __uint_as_float(((u32)u) << 16); }
__device__ __forceinline__ u16   f2bf(float f){
  u32 u = __float_as_uint(f);
  u += 0x7fffu + ((u >> 16) & 1u);
  return (u16)(u >> 16);
}
__device__ __forceinline__ f32x2 up2(u32 u){
  f32x2 r; r.x = bflo(u); r.y = bfhi(u); return r;
}

// ---------- dtype detector ----------
__global__ void detect_dtype(const u16* raw, int* flag){
  __shared__ int cnt;
  if (threadIdx.x == 0) cnt = 0;
  __syncthreads();
  int sane = 0;
  #pragma unroll
  for (int k = 0; k < 4; k++){
    u16 u = raw[threadIdx.x * 4 + k];
    int e = (u >> 7) & 0xff;
    if (e >= 100 && e <= 145) sane++;
  }
  atomicAdd(&cnt, sane);
  __syncthreads();
  if (threadIdx.x == 0) *flag = (cnt >= 870) ? 1 : 0;
}

// ---------- fused weight conversion (+ perm zeroing folded in) ----------
__global__ void cvt_all(const void* qw, const void* nw, const void* kw, const void* vw,
                        const void* tw, const void* lgp, const void* lbp,
                        u16* __restrict__ qwc, u16* __restrict__ nwc, u16* __restrict__ kvw,
                        float* __restrict__ twf, float* __restrict__ gbf,
                        int* __restrict__ perm,
                        const int* __restrict__ flag){
  int b = blockIdx.x, t = threadIdx.x;
  if (b >= 3082){
    perm[((b - 3082) << 8) + t] = 0;
    return;
  }
  int fl = *flag;
  if (b < 2048){
    const void* src = (b < 1024) ? qw : nw;
    u16* dst = (b < 1024) ? qwc : nwc;
    int i = ((b & 1023) << 8) + t;
    u16 v = fl ? ((const u16*)src)[i] : f2bf(((const float*)src)[i]);
    int mat = i >> 14, rem = i & 16383;
    dst[pkaddr(mat, rem >> 7, rem & 127)] = v;
  } else if (b < 3072){
    int r = b - 2048;
    int blk = r >> 9, half = (r >> 8) & 1;
    int i = ((r & 255) << 8) + t;                  // 0..65535 within (blk,half)
    const void* src = half ? vw : kw;
    size_t soff = (size_t)blk * 65536 + i;
    u16 v = fl ? ((const u16*)src)[soff] : f2bf(((const float*)src)[soff]);
    int mat = i >> 14, rem = i & 16383;
    kvw[(size_t)blk * 131072 + (size_t)half * 65536 + pkaddr(mat, rem >> 7, rem & 127)] = v;
  } else if (b < 3080){
    int i = ((b - 3072) << 8) + t;
    twf[i] = fl ? bf2f(((const u16*)tw)[i]) : ((const float*)tw)[i];
  } else if (b == 3080){
    gbf[t] = fl ? bf2f(((const u16*)lgp)[t]) : ((const float*)lgp)[t];
  } else {
    gbf[256 + t] = fl ? bf2f(((const u16*)lbp)[t]) : ((const float*)lbp)[t];
  }
}

// ---------- contention-free, deterministic key-bucket counting sort ----------
__global__ void khist_blk(const int* __restrict__ key_ids, int* __restrict__ blkcnt){
  __shared__ int c[8];
  int t = threadIdx.x, b = blockIdx.x;
  if (t < 8) c[t] = 0;
  __syncthreads();
  int n = b * 256 + t;
  if (n < N_NODES) atomicAdd(&c[key_ids[n]], 1);
  __syncthreads();
  if (t < 8) blkcnt[t * NBLK + b] = c[t];
}
__global__ void kscan2(const int* __restrict__ blkcnt, int* __restrict__ base,
                       int* __restrict__ tile_key){
  __shared__ int po[8];
  __shared__ int tot[8];
  int t = threadIdx.x;  // 64 threads
  if (t < 8){
    int s = 0;
    for (int b = 0; b < NBLK; b++) s += blkcnt[t * NBLK + b];
    tot[t] = s;
  }
  __syncthreads();
  if (t == 0){
    int off = 0;
    for (int k = 0; k < 8; k++){ po[k] = off; off += ((tot[k] + 127) >> 7) << 7; }
  }
  __syncthreads();
  if (t < 8){
    int run = po[t];
    for (int b = 0; b < NBLK; b++){ base[t * NBLK + b] = run; run += blkcnt[t * NBLK + b]; }
  }
  for (int tt = t; tt < NTILES; tt += 64){
    int row = tt << 7, k = 7;
    for (int kk = 1; kk < 8; kk++)
      if (row < po[kk]){ k = kk - 1; break; }
    tile_key[tt] = k;
  }
}
__global__ void scatter_perm2(const int* __restrict__ key_ids, const int* __restrict__ base,
                              int* __restrict__ perm, int* __restrict__ invperm){
  __shared__ unsigned char keyarr[256];
  int t = threadIdx.x, b = blockIdx.x;
  int n = b * 256 + t;
  int key = (n < N_NODES) ? key_ids[n] : 8;
  keyarr[t] = (unsigned char)key;
  __syncthreads();
  if (n >= N_NODES) return;
  int rank = 0;
  for (int j = 0; j < t; j++) rank += (keyarr[j] == (unsigned char)key);
  int pos = base[key * NBLK + b] + rank;
  perm[pos] = n;
  invperm[n] = pos;
}

// ---------- feat gather: f32 linear + hi/lo bf16 packed (also zeroes deg) ----------
__global__ void gather_feat(const void* emb_raw, const int* __restrict__ vid,
                            const int* __restrict__ perm, const int* __restrict__ flag,
                            float* __restrict__ feat, u16* __restrict__ fhi,
                            u16* __restrict__ flo, int* __restrict__ deg){
  int i = blockIdx.x * 256 + threadIdx.x;          // NPAD*128 exact
  int n = i >> 7, d = i & 127;
  if (d == 0) deg[n] = 0;
  int e = (vid[perm[n]] << 7) + d;
  float v = (*flag) ? bf2f(((const u16*)emb_raw)[e]) : ((const float*)emb_raw)[e];
  feat[i] = v;
  u16 h = f2bf(v);
  size_t pa = pkaddr(n >> 7, n & 127, d);
  fhi[pa] = h;
  flo[pa] = f2bf(v - bf2f(h));
}

// ---------- CSR build (perm space) ----------
__global__ void hist_dst(const int* __restrict__ dst, const int* __restrict__ invp,
                         int* __restrict__ deg){
  int e = blockIdx.x * 256 + threadIdx.x;
  if (e < N_EDGES) atomicAdd(&deg[invp[dst[e]]], 1);
}
// parallel two-level exclusive scan of deg -> rs/cur
__global__ void dsum_blk(const int* __restrict__ deg, int* __restrict__ dsum){
  __shared__ int s[256];
  int t = threadIdx.x, b = blockIdx.x;
  s[t] = deg[b * 256 + t];
  __syncthreads();
  for (int off = 128; off > 0; off >>= 1){
    if (t < off) s[t] += s[t + off];
    __syncthreads();
  }
  if (t == 0) dsum[b] = s[0];
}
__global__ void dscan_write(const int* __restrict__ deg, const int* __restrict__ dsum,
                            int* __restrict__ rs, int* __restrict__ cur){
  __shared__ int sb[256];
  __shared__ int sd[256];
  int t = threadIdx.x, b = blockIdx.x;
  // base = sum of dsum[0..b)  (b < NSBLK=200 < 256)
  sb[t] = (t < b) ? dsum[t] : 0;
  __syncthreads();
  for (int off = 128; off > 0; off >>= 1){
    if (t < off) sb[t] += sb[t + off];
    __syncthreads();
  }
  int base = sb[0];
  int n = b * 256 + t;
  int v = deg[n];
  sd[t] = v;
  __syncthreads();
  // inclusive Hillis-Steele scan over the block's 256 degrees
  for (int off = 1; off < 256; off <<= 1){
    int x = (t >= off) ? sd[t - off] : 0;
    __syncthreads();
    sd[t] += x;
    __syncthreads();
  }
  int r = base + sd[t] - v;   // exclusive prefix
  rs[n] = r;
  cur[n] = r;
}
__global__ void scatter_edges(const int* __restrict__ src, const int* __restrict__ dst,
                              const int* __restrict__ et, const int* __restrict__ invp,
                              int* __restrict__ cur, u32* __restrict__ epk){
  int e = blockIdx.x * 256 + threadIdx.x;
  if (e >= N_EDGES) return;
  int pos = atomicAdd(&cur[invp[dst[e]]], 1);
  epk[pos] = ((u32)invp[src[e]] << 2) | (u32)et[e];
}
// canonicalize within-node edge order (determinism). LDS-cached insertion sort.
__global__ __launch_bounds__(256) void sort_csr(const int* __restrict__ rs,
                                                const int* __restrict__ deg,
                                                u32* __restrict__ epk){
  __shared__ u32 buf[256 * SCAP];
  int t = threadIdx.x;
  int n = blockIdx.x * 256 + t;
  if (n >= NPAD) return;
  int s = rs[n], c = deg[n];
  if (c <= 1) return;
  if (c <= SCAP){
    u32* b = buf + t * SCAP;
    for (int i = 0; i < c; i++) b[i] = epk[s + i];
    for (int i = 1; i < c; i++){
      u32 v = b[i];
      int j = i - 1;
      while (j >= 0 && b[j] > v){ b[j + 1] = b[j]; j--; }
      b[j + 1] = v;
    }
    for (int i = 0; i < c; i++) epk[s + i] = b[i];
  } else {
    for (int i = 1; i < c; i++){
      u32 v = epk[s + i];
      int j = i - 1;
      while (j >= 0 && epk[s + j] > v){ epk[s + j + 1] = epk[s + j]; j--; }
      epk[s + j + 1] = v;
    }
  }
}

// ---------- unified q+kv MFMA GEMM, packed operands, XCD-affine swizzle ----------
// VERIFIED single-phase epilogue. Two-phase LDS-halving variants failed the
// harness twice (round 7 first-check; round 8 replay-nondeterminism) despite
// passing source-level race audits — do not reintroduce.
__global__ __launch_bounds__(256) void gemm_qkv(
    const u16* __restrict__ Ahi, const u16* __restrict__ Alo,
    const u16* __restrict__ Qw, const u16* __restrict__ KVw,
    const int* __restrict__ tkey, u16* __restrict__ C)
{
  __shared__ u16 sc[128 * LDW];
  int id = blockIdx.x;
  int xcd = id & 7, wi = id >> 3;        // wi in [0,450)
  int cy = xcd * 50 + wi / 9;            // row tile
  int cx = wi % 9;                       // column tile: 0=q, 1..8=kv
  int m0 = cy * 128;
  const u16* Bte = (cx == 0) ? (Qw + (size_t)tkey[cy] * 16384)
                             : (KVw + (size_t)(cx - 1) * 16384);
  const u16* Ath = Ahi + (size_t)cy * 16384;
  const u16* Atl = Alo + (size_t)cy * 16384;
  int w = threadIdx.x >> 6, l = threadIdx.x & 63;
  int wm = (w & 1) * 64, wn = (w >> 1) * 64;
  int lr = l & 15, lg = l >> 4;
  floatx4 acc[4][4] = {};
  #pragma unroll
  for (int kk = 0; kk < 4; kk++){
    int cc10 = (kk * 4 + lg) << 10;      // chunk base in packed tile
    short8 ah[4], al[4], bfr[4];
    #pragma unroll
    for (int i = 0; i < 4; i++){
      int off = cc10 + ((wm + i * 16 + lr) << 3);
      ah[i] = *(const short8*)(Ath + off);
      al[i] = *(const short8*)(Atl + off);
    }
    #pragma unroll
    for (int j = 0; j < 4; j++)
      bfr[j] = *(const short8*)(Bte + cc10 + ((wn + j * 16 + lr) << 3));
    #pragma unroll
    for (int i = 0; i < 4; i++)
      #pragma unroll
      for (int j = 0; j < 4; j++){
        acc[i][j] = __builtin_amdgcn_mfma_f32_16x16x32_bf16(ah[i], bfr[j], acc[i][j], 0, 0, 0);
        acc[i][j] = __builtin_amdgcn_mfma_f32_16x16x32_bf16(al[i], bfr[j], acc[i][j], 0, 0, 0);
      }
  }
  #pragma unroll
  for (int i = 0; i < 4; i++)
    #pragma unroll
    for (int j = 0; j < 4; j++)
      #pragma unroll
      for (int r = 0; r < 4; r++)
        sc[(wm + i * 16 + lg * 4 + r) * LDW + wn + j * 16 + lr] = f2bf(acc[i][j][r]);
  __syncthreads();
  int tr = threadIdx.x >> 4, tc = (threadIdx.x & 15) * 8;
  int cbase = cx * 128;   // q at cols 0..127, kv at 128..1151
  #pragma unroll
  for (int it = 0; it < 8; it++){
    int row = tr + it * 16;
    short8 vv = *(const short8*)(sc + row * LDW + tc);
    *(short8*)(C + (size_t)(m0 + row) * QKVW + cbase + tc) = vv;
  }
}

// ---------- fused node GEMM (packed hi/lo A) + relu + f32 LN + residual ----------
__global__ __launch_bounds__(256) void gemm_h_ln(
    const u16* __restrict__ Ahi, const u16* __restrict__ Alo,
    const u16* __restrict__ Bt, const int* __restrict__ tkey,
    const float* __restrict__ gbf,
    float* __restrict__ feat, u16* __restrict__ fhi, u16* __restrict__ flo, int blk)
{
  __shared__ float scf[64 * LDWF];
  int m0 = blockIdx.x * 64;
  int tile = blockIdx.x >> 1, rbase = (blockIdx.x & 1) * 64;
  const u16* Bte = Bt + (size_t)tkey[tile] * 16384;
  const u16* Ath = Ahi + (size_t)tile * 16384;
  const u16* Atl = Alo + (size_t)tile * 16384;
  int w = threadIdx.x >> 6, l = threadIdx.x & 63;
  int wn = w * 32;
  int lr = l & 15, lg = l >> 4;
  floatx4 acc[4][2] = {};
  #pragma unroll
  for (int kk = 0; kk < 4; kk++){
    int cc10 = (kk * 4 + lg) << 10;
    short8 ah[4], al[4], bfr[2];
    #pragma unroll
    for (int i = 0; i < 4; i++){
      int off = cc10 + ((rbase + i * 16 + lr) << 3);
      ah[i] = *(const short8*)(Ath + off);
      al[i] = *(const short8*)(Atl + off);
    }
    #pragma unroll
    for (int j = 0; j < 2; j++)
      bfr[j] = *(const short8*)(Bte + cc10 + ((wn + j * 16 + lr) << 3));
    #pragma unroll
    for (int i = 0; i < 4; i++)
      #pragma unroll
      for (int j = 0; j < 2; j++){
        acc[i][j] = __builtin_amdgcn_mfma_f32_16x16x32_bf16(ah[i], bfr[j], acc[i][j], 0, 0, 0);
        acc[i][j] = __builtin_amdgcn_mfma_f32_16x16x32_bf16(al[i], bfr[j], acc[i][j], 0, 0, 0);
      }
  }
  #pragma unroll
  for (int i = 0; i < 4; i++)
    #pragma unroll
    for (int j = 0; j < 2; j++)
      #pragma unroll
      for (int r = 0; r < 4; r++)
        scf[(i * 16 + lg * 4 + r) * LDWF + wn + j * 16 + lr] = acc[i][j][r];
  __syncthreads();
  int r = threadIdx.x >> 2, q4 = (threadIdx.x & 3) * 32;
  const float* srow = scf + r * LDWF + q4;
  float s1 = 0.f, s2 = 0.f;
  #pragma unroll
  for (int c = 0; c < 32; c++){
    float v = fmaxf(srow[c], 0.f);
    s1 += v; s2 += v * v;
  }
  s1 += __shfl_xor(s1, 1, 64); s1 += __shfl_xor(s1, 2, 64);
  s2 += __shfl_xor(s2, 1, 64); s2 += __shfl_xor(s2, 2, 64);
  float mu = s1 * (1.f / 128.f);
  float var = s2 * (1.f / 128.f) - mu * mu;
  float rstd = rsqrtf(var + 1e-5f);
  int n = m0 + r;
  int ntile = n >> 7, nr = n & 127;
  float* fr = feat + (size_t)n * 128 + q4;
  const float* gp = gbf + (blk << 7) + q4;
  #pragma unroll
  for (int c = 0; c < 32; c += 4){
    float4 fo = *(float4*)(fr + c);
    float y0 = (fmaxf(srow[c+0], 0.f) - mu) * rstd * gp[c+0] + gp[256 + c + 0] + fo.x;
    float y1 = (fmaxf(srow[c+1], 0.f) - mu) * rstd * gp[c+1] + gp[256 + c + 1] + fo.y;
    float y2 = (fmaxf(srow[c+2], 0.f) - mu) * rstd * gp[c+2] + gp[256 + c + 2] + fo.z;
    float y3 = (fmaxf(srow[c+3], 0.f) - mu) * rstd * gp[c+3] + gp[256 + c + 3] + fo.w;
    *(float4*)(fr + c) = make_float4(y0, y1, y2, y3);
    u16 h0 = f2bf(y0), h1 = f2bf(y1), h2 = f2bf(y2), h3 = f2bf(y3);
    size_t pa = pkaddr(ntile, nr, q4 + c);   // q4+c mult of 4 -> within one 8-chunk
    short4v ph; ph.x = (short)h0; ph.y = (short)h1; ph.z = (short)h2; ph.w = (short)h3;
    *(short4v*)(fhi + pa) = ph;
    short4v pl;
    pl.x = (short)f2bf(y0 - bf2f(h0)); pl.y = (short)f2bf(y1 - bf2f(h1));
    pl.z = (short)f2bf(y2 - bf2f(h2)); pl.w = (short)f2bf(y3 - bf2f(h3));
    *(short4v*)(flo + pa) = pl;
  }
}

// ---------- single-pass edge attention (16 lanes/node: 8 heads x 2 slots) ----------
// VERIFIED v2 structure — do not restructure (two equivalent-looking rewrites
// failed verification; see session journal).
__global__ __launch_bounds__(256) void edge_attn(
    const u16* __restrict__ qkv,
    const int* __restrict__ rs, const int* __restrict__ deg,
    const u32* __restrict__ epk, u16* __restrict__ agghi, u16* __restrict__ agglo)
{
  int n = blockIdx.x * 16 + (threadIdx.x >> 4);
  int l = threadIdx.x & 15;
  int h = l & 7, s = l >> 3;               // s in {0,1}
  const u16* qp = qkv + (size_t)n * QKVW + (h << 4);
  uint4 q0 = *(const uint4*)qp, q1 = *(const uint4*)(qp + 8);
  f32x2 qv[8];
  qv[0] = up2(q0.x); qv[1] = up2(q0.y); qv[2] = up2(q0.z); qv[3] = up2(q0.w);
  qv[4] = up2(q1.x); qv[5] = up2(q1.y); qv[6] = up2(q1.z); qv[7] = up2(q1.w);
  int e0 = rs[n], cnt = deg[n];
  float z = 0.f;
  f32x2 acc[8];
  #pragma unroll
  for (int j = 0; j < 8; j++){ acc[j].x = 0.f; acc[j].y = 0.f; }
  for (int base = 0; base < cnt; base += 4){
    int i0 = base + s, i1 = base + s + 2;
    bool p0 = i0 < cnt, p1 = i1 < cnt;
    // clamped, unconditional loads: inactive lanes re-read the last edge (L1 hit),
    // contribution zeroed via ew select. Keeps all 8 K/V loads in flight.
    u32 pk0 = epk[e0 + min(i0, cnt - 1)];
    u32 pk1 = epk[e0 + min(i1, cnt - 1)];
    const u16* kp0 = qkv + (size_t)(pk0 >> 2) * QKVW + 128 + ((pk0 & 3) << 7) + (h << 4);
    const u16* kp1 = qkv + (size_t)(pk1 >> 2) * QKVW + 128 + ((pk1 & 3) << 7) + (h << 4);
    uint4 ka0 = *(const uint4*)kp0, kb0 = *(const uint4*)(kp0 + 8);
    uint4 va0 = *(const uint4*)(kp0 + 512), vb0 = *(const uint4*)(kp0 + 520);
    uint4 ka1 = *(const uint4*)kp1, kb1 = *(const uint4*)(kp1 + 8);
    uint4 va1 = *(const uint4*)(kp1 + 512), vb1 = *(const uint4*)(kp1 + 520);
    f32x2 d0 = up2(ka0.x) * qv[0] + up2(ka0.y) * qv[1] + up2(ka0.z) * qv[2] + up2(ka0.w) * qv[3]
             + up2(kb0.x) * qv[4] + up2(kb0.y) * qv[5] + up2(kb0.z) * qv[6] + up2(kb0.w) * qv[7];
    f32x2 d1 = up2(ka1.x) * qv[0] + up2(ka1.y) * qv[1] + up2(ka1.z) * qv[2] + up2(ka1.w) * qv[3]
             + up2(kb1.x) * qv[4] + up2(kb1.y) * qv[5] + up2(kb1.z) * qv[6] + up2(kb1.w) * qv[7];
    float ew0 = p0 ? __expf(fminf((d0.x + d0.y) * 0.25f, 80.f)) : 0.f;
    float ew1 = p1 ? __expf(fminf((d1.x + d1.y) * 0.25f, 80.f)) : 0.f;
    z += ew0 + ew1;
    f32x2 w0v; w0v.x = ew0; w0v.y = ew0;
    f32x2 w1v; w1v.x = ew1; w1v.y = ew1;
    acc[0] += w0v * up2(va0.x); acc[1] += w0v * up2(va0.y);
    acc[2] += w0v * up2(va0.z); acc[3] += w0v * up2(va0.w);
    acc[4] += w0v * up2(vb0.x); acc[5] += w0v * up2(vb0.y);
    acc[6] += w0v * up2(vb0.z); acc[7] += w0v * up2(vb0.w);
    acc[0] += w1v * up2(va1.x); acc[1] += w1v * up2(va1.y);
    acc[2] += w1v * up2(va1.z); acc[3] += w1v * up2(va1.w);
    acc[4] += w1v * up2(vb1.x); acc[5] += w1v * up2(vb1.y);
    acc[6] += w1v * up2(vb1.z); acc[7] += w1v * up2(vb1.w);
  }
  // single butterfly round across the 2 slots (lane l <-> l^8)
  z += __shfl_xor(z, 8, 64);
  #pragma unroll
  for (int j = 0; j < 8; j++){
    acc[j].x += __shfl_xor(acc[j].x, 8, 64);
    acc[j].y += __shfl_xor(acc[j].y, 8, 64);
  }
  float inv = 1.f / (z + 1e-9f);
  float xv[8];
  if (s == 0){
    xv[0] = acc[0].x; xv[1] = acc[0].y; xv[2] = acc[1].x; xv[3] = acc[1].y;
    xv[4] = acc[2].x; xv[5] = acc[2].y; xv[6] = acc[3].x; xv[7] = acc[3].y;
  } else {
    xv[0] = acc[4].x; xv[1] = acc[4].y; xv[2] = acc[5].x; xv[3] = acc[5].y;
    xv[4] = acc[6].x; xv[5] = acc[6].y; xv[6] = acc[7].x; xv[7] = acc[7].y;
  }
  short8 ph, pl;
  #pragma unroll
  for (int k = 0; k < 8; k++){
    float y = xv[k] * inv;
    u16 hk = f2bf(y);
    ph[k] = (short)hk;
    pl[k] = (short)f2bf(y - bf2f(hk));
  }
  size_t pa = pkaddr(n >> 7, n & 127, (h << 4) + (s << 3));  // one aligned 8-chunk
  *(short8*)(agghi + pa) = ph;
  *(short8*)(agglo + pa) = pl;
}

// ---------- target readout ----------
__global__ __launch_bounds__(128) void readout(
    const float* __restrict__ feat, const float* __restrict__ twf,
    const int* __restrict__ key_ids, const int* __restrict__ invp,
    const int* __restrict__ tgt,
    float* __restrict__ outacc, void* dout, const int* __restrict__ flag, int blk)
{
  int t = threadIdx.x;
  int n = tgt[t];
  int key = key_ids[n];
  const float4* fr = (const float4*)(feat + (size_t)invp[n] * 128);
  const float4* wr = (const float4*)(twf + (size_t)((blk * 8 + key) << 7));
  float acc = 0.f;
  #pragma unroll
  for (int d = 0; d < 32; d++){
    float4 a = fr[d], b = wr[d];
    acc += a.x * b.x + a.y * b.y + a.z * b.z + a.w * b.w;
  }
  if (blk == 0){
    outacc[t] = 0.5f * acc;
  } else {
    float r = outacc[t] + 0.5f * acc;
    if (*flag) ((u16*)dout)[t] = f2bf(r);
    else       ((float*)dout)[t] = r;
  }
}

extern "C" void kernel_launch(void* const* d_in, const int* in_sizes, int n_in,
                              void* d_out, int out_size, void* d_ws, size_t ws_size,
                              hipStream_t stream)
{
  const void* emb = d_in[0];
  const void* qw  = d_in[1];
  const void* kw  = d_in[2];
  const void* vw  = d_in[3];
  const void* nw  = d_in[4];
  const void* tw  = d_in[5];
  const void* lg  = d_in[6];
  const void* lb  = d_in[7];
  const int* value_ids = (const int*)d_in[8];
  const int* key_ids   = (const int*)d_in[9];
  const int* srcp  = (const int*)d_in[10];
  const int* dstp  = (const int*)d_in[11];
  const int* etp   = (const int*)d_in[12];
  const int* tgt   = (const int*)d_in[13];

  char* p = (char*)d_ws;
  auto carve = [&](size_t bytes)->char*{
    char* r = p; p += (bytes + 255) & ~(size_t)255; return r;
  };
  int*   flag    = (int*)  carve(4);
  float* featp   = (float*)carve((size_t)NPAD * 128 * 4);
  u16*   feathi  = (u16*)  carve((size_t)NPAD * 128 * 2);
  u16*   featlo  = (u16*)  carve((size_t)NPAD * 128 * 2);
  u16*   qwc     = (u16*)  carve((size_t)2 * 1024 * 128 * 2);
  u16*   kvw     = (u16*)  carve((size_t)2 * 1024 * 128 * 2);
  u16*   nwc     = (u16*)  carve((size_t)2 * 1024 * 128 * 2);
  float* twf     = (float*)carve((size_t)2048 * 4);
  float* gbf     = (float*)carve((size_t)512 * 4);
  int*   blkcnt  = (int*)  carve((size_t)8 * NBLK * 4);
  int*   kbase   = (int*)  carve((size_t)8 * NBLK * 4);
  int*   tile_key= (int*)  carve(NTILES * 4);
  int*   perm    = (int*)  carve((size_t)NPAD * 4);
  int*   invperm = (int*)  carve((size_t)N_NODES * 4);
  int*   deg     = (int*)  carve((size_t)NPAD * 4);
  int*   rsx     = (int*)  carve((size_t)NPAD * 4);
  int*   cur     = (int*)  carve((size_t)NPAD * 4);
  int*   dsum    = (int*)  carve((size_t)NSBLK * 4);
  u32*   epk     = (u32*)  carve((size_t)N_EDGES * 4);
  u16*   qkvbuf  = (u16*)  carve((size_t)NPAD * QKVW * 2);
  u16*   agghi   = (u16*)  carve((size_t)NPAD * 128 * 2);
  u16*   agglo   = (u16*)  carve((size_t)NPAD * 128 * 2);
  float* outacc  = (float*)carve((size_t)N_TARGETS * 4);
  (void)ws_size; (void)n_in; (void)in_sizes; (void)out_size;

  detect_dtype<<<1, 256, 0, stream>>>((const u16*)emb, flag);

  // fused weight/param conversion + perm zeroing (replaces memset dispatch)
  cvt_all<<<3282, 256, 0, stream>>>(qw, nw, kw, vw, tw, lg, lb,
                                    qwc, nwc, kvw, twf, gbf, perm, flag);

  // deterministic key-bucket counting sort
  khist_blk<<<NBLK, 256, 0, stream>>>(key_ids, blkcnt);
  kscan2<<<1, 64, 0, stream>>>(blkcnt, kbase, tile_key);
  scatter_perm2<<<NBLK, 256, 0, stream>>>(key_ids, kbase, perm, invperm);

  gather_feat<<<(NPAD * 128) / 256, 256, 0, stream>>>(emb, value_ids, perm, flag,
                                                      featp, feathi, featlo, deg);

  // CSR in perm space; canonicalize per-node edge order for determinism
  const int eg = (N_EDGES + 255) / 256;
  hist_dst<<<eg, 256, 0, stream>>>(dstp, invperm, deg);
  dsum_blk<<<NSBLK, 256, 0, stream>>>(deg, dsum);
  dscan_write<<<NSBLK, 256, 0, stream>>>(deg, dsum, rsx, cur);
  scatter_edges<<<eg, 256, 0, stream>>>(srcp, dstp, etp, invperm, cur, epk);
  sort_csr<<<(NPAD + 255) / 256, 256, 0, stream>>>(rsx, deg, epk);

  for (int b = 0; b < NUM_BLOCKS; b++){
    gemm_qkv<<<3600, 256, 0, stream>>>(feathi, featlo,
                                       qwc + (size_t)b * 1024 * 128,
                                       kvw + (size_t)b * 1024 * 128,
                                       tile_key, qkvbuf);
    edge_attn<<<NPAD / 16, 256, 0, stream>>>(qkvbuf, rsx, deg, epk, agghi, agglo);
    gemm_h_ln<<<NPAD / 64, 256, 0, stream>>>(agghi, agglo,
                                             nwc + (size_t)b * 1024 * 128,
                                             tile_key, gbf, featp, feathi, featlo, b);
    readout<<<1, 128, 0, stream>>>(featp, twf, key_ids, invperm, tgt, outacc, d_out, flag, b);
  }
}